// Round 5
// baseline (7480.030 us; speedup 1.0000x reference)
//
#include <hip/hip_runtime.h>
#include <math.h>

#define TT 96
#define BB 128
#define DD 800
#define LL 128

typedef _Float16 h2v __attribute__((ext_vector_type(2)));

__device__ __forceinline__ h2v u2h(unsigned u) {
  union { unsigned u; h2v h; } x; x.u = u; return x.h;
}
__device__ __forceinline__ float fdot2(unsigned w, unsigned v, float acc) {
  return __builtin_amdgcn_fdot2(u2h(w), u2h(v), acc, false);
}
__device__ __forceinline__ unsigned packf16(float a, float b) {
  union { _Float16 h[2]; unsigned u; } x;
  x.h[0] = (_Float16)a; x.h[1] = (_Float16)b;
  return x.u;
}
__device__ __forceinline__ float sigm(float x) { return 1.f/(1.f + __expf(-x)); }
__device__ __forceinline__ float hsum4(float4 a) { return (a.x + a.y) + (a.z + a.w); }

__device__ __forceinline__ void dotacc4(uint4 wv, uint4 vv, float4& av) {
  av.x = fdot2(wv.x, vv.x, av.x);
  av.y = fdot2(wv.y, vv.y, av.y);
  av.z = fdot2(wv.z, vv.z, av.z);
  av.w = fdot2(wv.w, vv.w, av.w);
}

// ---------------- prep ----------------
__global__ void prep_misc(const float* __restrict__ b_ih, const float* __restrict__ b_hh,
                          float* __restrict__ b_lstm, double* __restrict__ accum) {
  int t = threadIdx.x;
  if (t < 512) b_lstm[t] = b_ih[t] + b_hh[t];
  if (t == 0) accum[0] = 0.0;
}

// f16 interleaved pack: dst[((k>>3)*J + j)*4 + ((k>>1)&3)] = pack(src[j*rs+k0+k], src[j*rs+k0+k+1])
__global__ void prep_pack_f16(const float* __restrict__ src, unsigned* __restrict__ dst,
                              int J, int rs, int k0, int total) {
  int idx = blockIdx.x * 256 + threadIdx.x;
  if (idx >= total) return;
  int u = idx & 3;
  int t2 = idx >> 2;
  int k8 = t2 / J;
  int j = t2 - k8 * J;
  int k = k8 * 8 + u * 2;
  const float* r = src + (size_t)j * rs + k0 + k;
  dst[idx] = packf16(r[0], r[1]);
}

// fp32 interleaved transpose (for W_px)
__global__ void prep_transpose(const float* __restrict__ src, float* __restrict__ dst,
                               int J, int rs, int k0, int total) {
  int idx = blockIdx.x * 256 + threadIdx.x;
  if (idx >= total) return;
  int J4 = J * 4;
  int k4 = idx / J4;
  int rem = idx - k4 * J4;
  int j = rem >> 2;
  int kk = rem & 3;
  dst[idx] = src[j * rs + k0 + k4 * 4 + kk];
}

// ---------------- phase 0: x_hat (emits f16-packed pairs) ----------------
__device__ __forceinline__ float dot4(float4 w, float4 v) {
  return w.x*v.x + w.y*v.y + w.z*v.z + w.w*v.w;
}
__global__ __launch_bounds__(256) void xhat_kernel(const float* __restrict__ x,
                                                   const float* __restrict__ Wpx4,
                                                   const float* __restrict__ b_px,
                                                   unsigned* __restrict__ xhat2) {
  __shared__ __align__(16) float sx[8][800];
  const int wg = blockIdx.x, tid = threadIdx.x;
  const int p0 = wg * 8;
  for (int r = 0; r < 8; ++r) {
    int p = p0 + r; int t = p >> 7; int b = p & 127;
    const float* row = x + ((size_t)b * TT + t) * 800;
    for (int col = tid; col < 800; col += 256) sx[r][col] = row[col];
  }
  __syncthreads();
  const int j = tid & 127, g = tid >> 7;
  float acc[4];
  const float bj = b_px[j];
  #pragma unroll
  for (int u = 0; u < 4; ++u) acc[u] = bj;
  const float4* W = (const float4*)Wpx4;
  #pragma unroll 2
  for (int k4 = 0; k4 < 200; ++k4) {
    float4 w = W[k4 * 128 + j];
    #pragma unroll
    for (int u = 0; u < 4; ++u) {
      float4 xv = *(const float4*)&sx[g + 2*u][k4 * 4];
      acc[u] += dot4(w, xv);
    }
  }
  #pragma unroll
  for (int u = 0; u < 4; ++u) {
    float v = fmaxf(acc[u], 0.f);
    float vp = __shfl_xor(v, 1, 64);    // partner lane j^1 (same wave)
    if ((j & 1) == 0) {
      int p = p0 + g + 2*u;
      xhat2[(size_t)p * 64 + (j >> 1)] = packf16(v, vp);
    }
  }
}

// ---------------- phase 1: sequential scan, 1024 threads/WG, K-split rows ----------------
// Every row is computed by 2 threads (kh = tid>>9 owns a K-half). Per-thread
// register weight arrays are 8 uint4 (32 VGPR) and reloaded per timestep ->
// short live ranges, no scratch spill at the 128-VGPR cap of a 1024-thr block.
__global__ __launch_bounds__(1024) void phase1_kernel(
    const float* __restrict__ eps, const unsigned* __restrict__ xhat2g,
    const uint4* __restrict__ Wpr4, const float* __restrict__ b_pr,
    const uint4* __restrict__ Wen4, const float* __restrict__ b_en,
    const uint4* __restrict__ Wpz4, const float* __restrict__ b_pz,
    const uint4* __restrict__ Wihx4, const uint4* __restrict__ Wihz4,
    const uint4* __restrict__ Whh4, const float* __restrict__ b_lstm,
    float* __restrict__ g_out, float* __restrict__ g_muq, float* __restrict__ g_sgq,
    float* __restrict__ g_mup, float* __restrict__ g_sgp)
{
  __shared__ __align__(16) float s_gz[10240];      // [10][1024] gate K-half partials (also pe-partial scratch)
  __shared__ __align__(16) _Float16 s_z2[1280];
  __shared__ __align__(16) _Float16 s_zh2[1280];
  __shared__ __align__(16) float s_out[128];
  __shared__ __align__(16) float s_ehmu[128];
  __shared__ __align__(16) float s_mup[128];
  __shared__ __align__(16) float s_sgp[128];
  __shared__ __align__(16) float s_sgq[128];
  __shared__ __align__(16) unsigned s_out2[64];
  __shared__ __align__(16) unsigned s_xh2[64];
  __shared__ __align__(16) _Float16 s_h2[128];

  const int tid = threadIdx.x;
  const int b = blockIdx.x;
  const int row = tid & 511;     // gate/pe row
  const int kh = tid >> 9;       // K-half this thread owns

  if (tid < 128) { s_out[tid] = 0.f; s_h2[tid] = (_Float16)0.f; }
  float c_reg = 0.f;
  const float blst_h = (kh == 0) ? b_lstm[row] : 0.f;
  const float bias_pe = (kh == 0) ? ((row < 256) ? b_pr[row] : b_en[row - 256]) : 0.f;
  const float bpz = b_pz[tid & 127];

  const uint4* WprP = Wpr4 + kh * 8 * 256 + row;          // valid when row<256
  const uint4* WenP = Wen4 + kh * 16 * 256 + (row - 256); // valid when row>=256
  const uint4* WxP  = Wihx4 + kh * 8 * 512 + row;
  const uint4* WzP  = Wihz4 + kh * 8 * 512 + row;
  const uint4* WhP  = Whh4  + kh * 8 * 512 + row;

  for (int t = 0; t < TT; ++t) {
    const size_t pb = (size_t)t * BB + b;
    const float* epsb = eps + pb * 1280;
    // prefetch globals for this timestep (no barrier dependence)
    unsigned xh_pref = 0;
    if (tid >= 192 && tid < 256) xh_pref = xhat2g[pb * 64 + (tid - 192)];
    float e0 = epsb[tid];
    float e1 = (tid < 256) ? epsb[1024 + tid] : 0.f;

    __syncthreads();                       // B0: prev-timestep s_out/s_h2 visible
    float oacc = 0.f;
    if (tid < 128) {
      g_out[pb * 128 + tid] = s_out[tid];
    } else if (tid < 192) {
      int m = tid - 128;
      s_out2[m] = packf16(s_out[2*m], s_out[2*m + 1]);
    } else if (tid < 256) {
      s_xh2[tid - 192] = xh_pref;
    }
    __syncthreads();                       // B1

    // prior/encoder K-half partials (all 1024 threads)
    {
      float4 a4 = {bias_pe, 0.f, 0.f, 0.f};
      if (row < 256) {          // prior: K=128, this half = k8 in [kh*8, kh*8+8)
        #pragma unroll
        for (int q = 0; q < 8; ++q) {
          uint4 w = WprP[q * 256];
          uint4 o = *(const uint4*)&s_out2[(kh * 8 + q) * 4];
          dotacc4(w, o, a4);
        }
      } else {                  // encoder: K=256; kh=0 -> out, kh=1 -> xhat
        const unsigned* vecs = kh ? s_xh2 : s_out2;
        #pragma unroll
        for (int q = 0; q < 16; ++q) {
          uint4 w = WenP[q * 256];
          uint4 o = *(const uint4*)&vecs[q * 4];
          dotacc4(w, o, a4);
        }
      }
      s_gz[tid] = hsum4(a4);
    }
    __syncthreads();                       // B2
    if (tid < 512) {                       // combine halves + nonlinearities
      float v = s_gz[tid] + s_gz[tid + 512];
      if (tid < 128) {
        float ph = fmaxf(v, 0.f);
        s_mup[tid] = ph; g_mup[pb * 128 + tid] = ph;
      } else if (tid < 256) {
        float ph = fmaxf(v, 0.f);
        float y = expf(ph) + 0.5f;
        float sp = (y > 20.f) ? y : log1pf(expf(y));
        s_sgp[tid - 128] = sp; g_sgp[pb * 128 + tid - 128] = sp;
      } else if (tid < 384) {
        s_ehmu[tid - 256] = fmaxf(v, 0.f);
      } else {
        float sq = expf(fmaxf(v, 0.f));
        s_sgq[tid - 384] = sq; g_sgq[pb * 128 + tid - 384] = sq;
      }
    }
    __syncthreads();                       // B3

    // z (f16 into LDS) from prefetched eps + g_muq
    {
      int l = tid & 127;
      float mu = s_ehmu[l] + s_mup[l];
      float sq = s_sgq[l];
      s_z2[tid] = (_Float16)(mu + sq * e0);
      if (tid < 256) s_z2[1024 + tid] = (_Float16)(mu + sq * e1);
      if (tid < 128) g_muq[pb * 128 + tid] = mu;
    }
    __syncthreads();                       // B4

    // z_hat: row-sample rs=tid (full K, W_pz f16 global stream); tid<256 also rs+1024
    {
      int s = tid >> 7, j = tid & 127;
      float4 a0 = {bpz, 0.f, 0.f, 0.f}, a1 = {bpz, 0.f, 0.f, 0.f};
      const uint4* Wz = Wpz4 + j;
      #pragma unroll
      for (int q = 0; q < 16; ++q) {
        uint4 w = Wz[q * 128];
        uint4 z0 = *(const uint4*)&s_z2[s * 128 + q * 8];
        dotacc4(w, z0, a0);
        if (tid < 256) {
          uint4 z1 = *(const uint4*)&s_z2[(8 + s) * 128 + q * 8];
          dotacc4(w, z1, a1);
        }
      }
      s_zh2[s * 128 + j] = (_Float16)fmaxf(hsum4(a0), 0.f);
      if (tid < 256) s_zh2[(8 + s) * 128 + j] = (_Float16)fmaxf(hsum4(a1), 0.f);
    }
    // gates-x K-half partial (register)
    float gxp;
    {
      float4 a4 = {blst_h, 0.f, 0.f, 0.f};
      #pragma unroll
      for (int q = 0; q < 8; ++q) {
        uint4 w = WxP[q * 512];
        uint4 xv = *(const uint4*)&s_xh2[(kh * 8 + q) * 4];
        dotacc4(w, xv, a4);
      }
      gxp = hsum4(a4);
    }
    __syncthreads();                       // B5

    // gates-z K-half partials, 2 passes x 5 samples (streamed W_ihz)
    #pragma unroll
    for (int half = 0; half < 2; ++half) {
      float4 a5[5];
      #pragma unroll
      for (int s = 0; s < 5; ++s) a5[s] = float4{gxp, 0.f, 0.f, 0.f};
      #pragma unroll
      for (int q = 0; q < 8; ++q) {
        uint4 w = WzP[q * 512];
        #pragma unroll
        for (int s = 0; s < 5; ++s) {
          uint4 zv = *(const uint4*)&s_zh2[(half * 5 + s) * 128 + kh * 64 + q * 8];
          dotacc4(w, zv, a5[s]);
        }
      }
      #pragma unroll
      for (int s = 0; s < 5; ++s)
        s_gz[(half * 5 + s) * 1024 + tid] = hsum4(a5[s]);
    }
    // reload serial weights fresh each timestep: 32 VGPR, short live range
    uint4 whh8[8];
    #pragma unroll
    for (int q = 0; q < 8; ++q) whh8[q] = WhP[q * 512];
    __syncthreads();                       // B6

    // serial LSTM over 10 samples (register W_hh half-rows, broadcast h)
    for (int s = 0; s < 10; ++s) {
      float4 a4 = {s_gz[s * 1024 + tid], 0.f, 0.f, 0.f};
      #pragma unroll
      for (int q = 0; q < 8; ++q) {
        uint4 hv = *(const uint4*)&s_h2[kh * 64 + q * 8];
        dotacc4(whh8[q], hv, a4);
      }
      s_gz[s * 1024 + tid] = hsum4(a4);
      __syncthreads();
      if (tid < 128) {
        int base = s * 1024 + tid;
        float gi = s_gz[base]       + s_gz[base + 512];
        float gf = s_gz[base + 128] + s_gz[base + 640];
        float gg = s_gz[base + 256] + s_gz[base + 768];
        float go = s_gz[base + 384] + s_gz[base + 896];
        c_reg = sigm(gf) * c_reg + sigm(gi) * tanhf(gg);
        float h = sigm(go) * tanhf(c_reg);
        oacc += h;
        s_h2[tid] = (_Float16)h;
      }
      __syncthreads();
    }
    if (tid < 128) s_out[tid] = oacc * 0.1f;
  }
}

// ---------------- phase 2: ELBO terms, fully parallel ----------------
__global__ __launch_bounds__(256, 2) void phase2_kernel(
    const float* __restrict__ x, const float* __restrict__ beta_p,
    const float* __restrict__ eps,
    const float* __restrict__ g_out, const float* __restrict__ g_muq, const float* __restrict__ g_sgq,
    const float* __restrict__ g_mup, const float* __restrict__ g_sgp,
    const uint4* __restrict__ Wpz4, const float* __restrict__ b_pz,
    const uint4* __restrict__ Wdez4, const uint4* __restrict__ Wdeo4, const float* __restrict__ b_de,
    double* __restrict__ accum)
{
  __shared__ __align__(16) _Float16 s_z2[5120];
  __shared__ __align__(16) _Float16 s_zh2[5120];
  __shared__ __align__(16) unsigned s_out2[256];
  __shared__ __align__(16) float s_muq[512], s_sgq[512], s_mup[512], s_sgp[512];
  __shared__ float s_wred[4];

  const int tid = threadIdx.x;
  const int p0 = blockIdx.x * 4;        // 4 (t,b) pairs -> 40 sample rows
  const float beta = beta_p[0];
  float acc_loc = 0.f;

  for (int i = tid; i < 512; i += 256) {
    size_t gi = (size_t)p0 * 128 + i;
    s_muq[i] = g_muq[gi]; s_sgq[i] = g_sgq[gi];
    s_mup[i] = g_mup[gi]; s_sgp[i] = g_sgp[gi];
  }
  {
    int pair = tid >> 6, m = tid & 63;
    const float* o = g_out + (size_t)p0 * 128 + pair * 128;
    s_out2[tid] = packf16(o[2*m], o[2*m + 1]);
  }
  __syncthreads();

  // KL + z build ((z-muq)/sq == eps exactly)
  {
    int l = tid & 127;
    int ppb = tid >> 7;
    for (int q = 0; q < 2; ++q) {
      int pp = ppb + 2 * q;
      float mq = s_muq[pp*128 + l], sq = s_sgq[pp*128 + l];
      float mp = s_mup[pp*128 + l], spv = s_sgp[pp*128 + l];
      float inv_sp = 1.f / spv;
      float lsq = __logf(sq), lsp = __logf(spv);
      const float* ep = eps + (size_t)(p0 + pp) * 1280 + l;
      float kl = 0.f;
      #pragma unroll
      for (int s = 0; s < 10; ++s) {
        float e = ep[s * 128];
        float z = mq + sq * e;
        s_z2[(pp * 10 + s) * 128 + l] = (_Float16)z;
        float ap = (z - mp) * inv_sp;
        kl += (-0.5f * e * e - lsq) - (-0.5f * ap * ap - lsp);
      }
      acc_loc -= beta * kl;
    }
  }
  __syncthreads();

  // z_hat: 40 rows, W_pz f16 global stream, 20 rows per thread-group
  {
    int j = tid & 127, grp = tid >> 7;
    float acc[20];
    float bj = b_pz[j];
    #pragma unroll
    for (int u = 0; u < 20; ++u) acc[u] = bj;
    for (int k8 = 0; k8 < 16; ++k8) {
      uint4 w = Wpz4[k8 * 128 + j];
      #pragma unroll
      for (int u = 0; u < 20; ++u) {
        uint4 zv = *(const uint4*)&s_z2[(grp * 20 + u) * 128 + k8 * 8];
        acc[u] = fdot2(w.x, zv.x, acc[u]); acc[u] = fdot2(w.y, zv.y, acc[u]);
        acc[u] = fdot2(w.z, zv.z, acc[u]); acc[u] = fdot2(w.w, zv.w, acc[u]);
      }
    }
    #pragma unroll
    for (int u = 0; u < 20; ++u)
      s_zh2[(grp * 20 + u) * 128 + j] = (_Float16)fmaxf(acc[u], 0.f);
  }
  __syncthreads();

  // decoder + Bernoulli; weight rows register-cached (batched global loads)
  for (int dc = 0; dc < 4; ++dc) {
    int d = tid + 256 * dc;
    if (d < 800) {
      uint4 wrow[16];
      #pragma unroll
      for (int k8 = 0; k8 < 16; ++k8) wrow[k8] = Wdeo4[k8 * 800 + d];
      float acco[4] = {0.f, 0.f, 0.f, 0.f};
      #pragma unroll
      for (int k8 = 0; k8 < 16; ++k8) {
        uint4 w = wrow[k8];
        #pragma unroll
        for (int pp = 0; pp < 4; ++pp) {
          uint4 ov = *(const uint4*)&s_out2[pp * 64 + k8 * 4];
          acco[pp] = fdot2(w.x, ov.x, acco[pp]); acco[pp] = fdot2(w.y, ov.y, acco[pp]);
          acco[pp] = fdot2(w.z, ov.z, acco[pp]); acco[pp] = fdot2(w.w, ov.w, acco[pp]);
        }
      }
      #pragma unroll
      for (int k8 = 0; k8 < 16; ++k8) wrow[k8] = Wdez4[k8 * 800 + d];
      float bd = b_de[d];
      for (int pp = 0; pp < 4; ++pp) {
        float acc[10];
        #pragma unroll
        for (int s = 0; s < 10; ++s) acc[s] = 0.f;
        for (int k8 = 0; k8 < 16; ++k8) {
          uint4 w = wrow[k8];
          #pragma unroll
          for (int s = 0; s < 10; ++s) {
            uint4 zv = *(const uint4*)&s_zh2[(pp * 10 + s) * 128 + k8 * 8];
            acc[s] = fdot2(w.x, zv.x, acc[s]); acc[s] = fdot2(w.y, zv.y, acc[s]);
            acc[s] = fdot2(w.z, zv.z, acc[s]); acc[s] = fdot2(w.w, zv.w, acc[s]);
          }
        }
        int p = p0 + pp, tt2 = p >> 7, bb = p & 127;
        float xd = x[((size_t)bb * TT + tt2) * 800 + d];
        float base = acco[pp] + bd;
        #pragma unroll
        for (int s = 0; s < 10; ++s) {
          float lg = fmaxf(acc[s] + base, 0.f);
          acc_loc += xd * lg - lg - __logf(1.f + __expf(-lg));
        }
      }
    }
  }

  // block reduction -> one atomic per WG
  float v = acc_loc;
  #pragma unroll
  for (int off = 32; off > 0; off >>= 1) v += __shfl_down(v, off, 64);
  if ((tid & 63) == 0) s_wred[tid >> 6] = v;
  __syncthreads();
  if (tid == 0) {
    double tot = (double)s_wred[0] + (double)s_wred[1] + (double)s_wred[2] + (double)s_wred[3];
    atomicAdd(accum, tot);
  }
}

__global__ void finalize_kernel(const double* __restrict__ accum, float* __restrict__ out) {
  if (threadIdx.x == 0 && blockIdx.x == 0)
    out[0] = (float)(-accum[0] / 122880.0);   // B*T*S
}

// ---------------- host ----------------
extern "C" void kernel_launch(void* const* d_in, const int* in_sizes, int n_in,
                              void* d_out, int out_size, void* d_ws, size_t ws_size,
                              hipStream_t stream) {
  const float* x    = (const float*)d_in[0];
  const float* beta = (const float*)d_in[1];
  const float* eps  = (const float*)d_in[2];
  const float* W_px = (const float*)d_in[3];
  const float* b_px = (const float*)d_in[4];
  const float* W_pz = (const float*)d_in[5];
  const float* b_pz = (const float*)d_in[6];
  const float* W_pr = (const float*)d_in[7];
  const float* b_pr = (const float*)d_in[8];
  const float* W_en = (const float*)d_in[9];
  const float* b_en = (const float*)d_in[10];
  const float* W_de = (const float*)d_in[11];
  const float* b_de = (const float*)d_in[12];
  const float* W_ih = (const float*)d_in[13];
  const float* W_hh = (const float*)d_in[14];
  const float* b_ih = (const float*)d_in[15];
  const float* b_hh = (const float*)d_in[16];
  float* ws = (float*)d_ws;

  // ws offsets (in 4B units)
  constexpr size_t O_WPX  = 0;                      // 102400 fp32
  constexpr size_t O_WPR  = O_WPX  + 102400;        // 16384 uints
  constexpr size_t O_WEN  = O_WPR  + 16384;         // 32768
  constexpr size_t O_WPZ  = O_WEN  + 32768;         // 8192
  constexpr size_t O_WIHX = O_WPZ  + 8192;          // 32768
  constexpr size_t O_WIHZ = O_WIHX + 32768;         // 32768
  constexpr size_t O_WHH  = O_WIHZ + 32768;         // 32768
  constexpr size_t O_WDEZ = O_WHH  + 32768;         // 51200
  constexpr size_t O_WDEO = O_WDEZ + 51200;         // 51200
  constexpr size_t O_BL   = O_WDEO + 51200;         // 512
  constexpr size_t O_ACC  = O_BL   + 512;           // 2 (double)
  constexpr size_t O_XHAT = O_ACC  + 4;             // 786432 uints (f16-packed)
  constexpr size_t O_OUT  = O_XHAT + 1572864;
  constexpr size_t O_MUQ  = O_OUT  + 1572864;
  constexpr size_t O_SGQ  = O_MUQ  + 1572864;
  constexpr size_t O_MUP  = O_SGQ  + 1572864;
  constexpr size_t O_SGP  = O_MUP  + 1572864;
  (void)O_SGP;

  prep_misc<<<dim3(1), dim3(512), 0, stream>>>(b_ih, b_hh, ws + O_BL, (double*)(ws + O_ACC));

  auto pk = [&](const float* src, size_t off, int J, int rs, int k0, int K) {
    int total = J * (K / 2);
    prep_pack_f16<<<dim3((total + 255) / 256), dim3(256), 0, stream>>>(
        src, (unsigned*)(ws + off), J, rs, k0, total);
  };
  pk(W_pr, O_WPR, 256, 128, 0, 128);
  pk(W_en, O_WEN, 256, 256, 0, 256);
  pk(W_pz, O_WPZ, 128, 128, 0, 128);
  pk(W_ih, O_WIHX, 512, 256, 0, 128);
  pk(W_ih, O_WIHZ, 512, 256, 128, 128);
  pk(W_hh, O_WHH, 512, 128, 0, 128);
  pk(W_de, O_WDEZ, 800, 256, 0, 128);
  pk(W_de, O_WDEO, 800, 256, 128, 128);
  prep_transpose<<<dim3((102400 + 255) / 256), dim3(256), 0, stream>>>(
      W_px, ws + O_WPX, 128, 800, 0, 102400);

  xhat_kernel<<<dim3(1536), dim3(256), 0, stream>>>(x, ws + O_WPX, b_px, (unsigned*)(ws + O_XHAT));

  phase1_kernel<<<dim3(128), dim3(1024), 0, stream>>>(
      eps, (const unsigned*)(ws + O_XHAT),
      (const uint4*)(ws + O_WPR), b_pr, (const uint4*)(ws + O_WEN), b_en,
      (const uint4*)(ws + O_WPZ), b_pz, (const uint4*)(ws + O_WIHX),
      (const uint4*)(ws + O_WIHZ), (const uint4*)(ws + O_WHH), ws + O_BL,
      ws + O_OUT, ws + O_MUQ, ws + O_SGQ, ws + O_MUP, ws + O_SGP);

  phase2_kernel<<<dim3(3072), dim3(256), 0, stream>>>(
      x, beta, eps, ws + O_OUT, ws + O_MUQ, ws + O_SGQ, ws + O_MUP, ws + O_SGP,
      (const uint4*)(ws + O_WPZ), b_pz,
      (const uint4*)(ws + O_WDEZ), (const uint4*)(ws + O_WDEO), b_de,
      (double*)(ws + O_ACC));

  finalize_kernel<<<dim3(1), dim3(64), 0, stream>>>((const double*)(ws + O_ACC), (float*)d_out);
}

// Round 6
// 4981.888 us; speedup vs baseline: 1.5014x; 1.5014x over previous
//
#include <hip/hip_runtime.h>
#include <math.h>

#define TT 96
#define BB 128
#define DD 800
#define LL 128

typedef _Float16 h2v __attribute__((ext_vector_type(2)));

__device__ __forceinline__ h2v u2h(unsigned u) {
  union { unsigned u; h2v h; } x; x.u = u; return x.h;
}
__device__ __forceinline__ float fdot2(unsigned w, unsigned v, float acc) {
  return __builtin_amdgcn_fdot2(u2h(w), u2h(v), acc, false);
}
__device__ __forceinline__ unsigned packf16(float a, float b) {
  union { _Float16 h[2]; unsigned u; } x;
  x.h[0] = (_Float16)a; x.h[1] = (_Float16)b;
  return x.u;
}
__device__ __forceinline__ float sigm(float x) { return 1.f/(1.f + __expf(-x)); }
__device__ __forceinline__ float hsum4(float4 a) { return (a.x + a.y) + (a.z + a.w); }

__device__ __forceinline__ void dotacc4(uint4 wv, uint4 vv, float4& av) {
  av.x = fdot2(wv.x, vv.x, av.x);
  av.y = fdot2(wv.y, vv.y, av.y);
  av.z = fdot2(wv.z, vv.z, av.z);
  av.w = fdot2(wv.w, vv.w, av.w);
}

// ---------------- prep ----------------
__global__ void prep_misc(const float* __restrict__ b_ih, const float* __restrict__ b_hh,
                          float* __restrict__ b_lstm, double* __restrict__ accum) {
  int t = threadIdx.x;
  if (t < 512) b_lstm[t] = b_ih[t] + b_hh[t];
  if (t == 0) accum[0] = 0.0;
}

// f16 interleaved pack: dst[((k>>3)*J + j)*4 + ((k>>1)&3)] = pack(src[j*rs+k0+k], src[j*rs+k0+k+1])
__global__ void prep_pack_f16(const float* __restrict__ src, unsigned* __restrict__ dst,
                              int J, int rs, int k0, int total) {
  int idx = blockIdx.x * 256 + threadIdx.x;
  if (idx >= total) return;
  int u = idx & 3;
  int t2 = idx >> 2;
  int k8 = t2 / J;
  int j = t2 - k8 * J;
  int k = k8 * 8 + u * 2;
  const float* r = src + (size_t)j * rs + k0 + k;
  dst[idx] = packf16(r[0], r[1]);
}

// fp32 interleaved transpose (for W_px)
__global__ void prep_transpose(const float* __restrict__ src, float* __restrict__ dst,
                               int J, int rs, int k0, int total) {
  int idx = blockIdx.x * 256 + threadIdx.x;
  if (idx >= total) return;
  int J4 = J * 4;
  int k4 = idx / J4;
  int rem = idx - k4 * J4;
  int j = rem >> 2;
  int kk = rem & 3;
  dst[idx] = src[j * rs + k0 + k4 * 4 + kk];
}

// ---------------- phase 0: x_hat (emits f16-packed pairs) ----------------
__device__ __forceinline__ float dot4(float4 w, float4 v) {
  return w.x*v.x + w.y*v.y + w.z*v.z + w.w*v.w;
}
__global__ __launch_bounds__(256) void xhat_kernel(const float* __restrict__ x,
                                                   const float* __restrict__ Wpx4,
                                                   const float* __restrict__ b_px,
                                                   unsigned* __restrict__ xhat2) {
  __shared__ __align__(16) float sx[8][800];
  const int wg = blockIdx.x, tid = threadIdx.x;
  const int p0 = wg * 8;
  for (int r = 0; r < 8; ++r) {
    int p = p0 + r; int t = p >> 7; int b = p & 127;
    const float* row = x + ((size_t)b * TT + t) * 800;
    for (int col = tid; col < 800; col += 256) sx[r][col] = row[col];
  }
  __syncthreads();
  const int j = tid & 127, g = tid >> 7;
  float acc[4];
  const float bj = b_px[j];
  #pragma unroll
  for (int u = 0; u < 4; ++u) acc[u] = bj;
  const float4* W = (const float4*)Wpx4;
  #pragma unroll 2
  for (int k4 = 0; k4 < 200; ++k4) {
    float4 w = W[k4 * 128 + j];
    #pragma unroll
    for (int u = 0; u < 4; ++u) {
      float4 xv = *(const float4*)&sx[g + 2*u][k4 * 4];
      acc[u] += dot4(w, xv);
    }
  }
  #pragma unroll
  for (int u = 0; u < 4; ++u) {
    float v = fmaxf(acc[u], 0.f);
    float vp = __shfl_xor(v, 1, 64);    // partner lane j^1 (same wave)
    if ((j & 1) == 0) {
      int p = p0 + g + 2*u;
      xhat2[(size_t)p * 64 + (j >> 1)] = packf16(v, vp);
    }
  }
}

// ---------------- phase 1: sequential scan, one WG (512 thr) per batch chain ----------------
// amdgpu_waves_per_eu(2,2) pins the register allocator to a 256-VGPR budget
// (512-thread block = 8 waves = exactly 2/EU at 1 block/CU). whh[16]+wihz[16]
// (128 VGPRs of persistent weights) + ~70 transient fits with no scratch spill.
__global__ __attribute__((amdgpu_flat_work_group_size(512, 512)))
__attribute__((amdgpu_waves_per_eu(2, 2))) void phase1_kernel(
    const float* __restrict__ eps, const unsigned* __restrict__ xhat2g,
    const uint4* __restrict__ Wpr4, const float* __restrict__ b_pr,
    const uint4* __restrict__ Wen4, const float* __restrict__ b_en,
    const uint4* __restrict__ Wpz4, const float* __restrict__ b_pz,
    const uint4* __restrict__ Wihx4, const uint4* __restrict__ Wihz4,
    const uint4* __restrict__ Whh4, const float* __restrict__ b_lstm,
    float* __restrict__ g_out, float* __restrict__ g_muq, float* __restrict__ g_sgq,
    float* __restrict__ g_mup, float* __restrict__ g_sgp)
{
  __shared__ __align__(16) unsigned s_wpz[8192];   // W_pz f16, LDS-resident (32 KB)
  __shared__ __align__(16) float s_gz[5120];       // gates per sample [10][512]
  __shared__ __align__(16) _Float16 s_z2[1280];
  __shared__ __align__(16) _Float16 s_zh2[1280];
  __shared__ __align__(16) float s_out[128];
  __shared__ __align__(16) float s_ehmu[128];
  __shared__ __align__(16) float s_mup[128];
  __shared__ __align__(16) float s_sgp[128];
  __shared__ __align__(16) float s_sgq[128];
  __shared__ __align__(16) unsigned s_out2[64];
  __shared__ __align__(16) unsigned s_xh2[64];
  __shared__ __align__(16) _Float16 s_h2[128];

  const int tid = threadIdx.x;
  const int b = blockIdx.x;

  // persistent register weight rows (reused 10x per timestep, 96 timesteps)
  uint4 whh[16], wihz[16];
  #pragma unroll
  for (int k8 = 0; k8 < 16; ++k8) {
    whh[k8]  = Whh4[k8 * 512 + tid];
    wihz[k8] = Wihz4[k8 * 512 + tid];
  }
  for (int i = tid; i < 8192; i += 512) s_wpz[i] = ((const unsigned*)Wpz4)[i];
  if (tid < 128) { s_out[tid] = 0.f; s_h2[tid] = (_Float16)0.f; }
  float c_reg = 0.f;
  const float blst = b_lstm[tid];
  const float bias_pe = (tid < 256) ? b_pr[tid] : b_en[tid - 256];
  const float bpz = b_pz[tid & 127];

  for (int t = 0; t < TT; ++t) {
    const size_t pb = (size_t)t * BB + b;
    const float* epsb = eps + pb * 1280;
    // prefetch globals for this timestep (no barrier dependence)
    unsigned xh_pref = 0;
    if (tid >= 192 && tid < 256) xh_pref = xhat2g[pb * 64 + (tid - 192)];
    float e0 = epsb[tid];
    float e1 = epsb[tid + 512];
    float e2 = (tid < 256) ? epsb[tid + 1024] : 0.f;

    __syncthreads();                       // B0: prev-timestep s_out/s_h2 visible
    float oacc = 0.f;
    if (tid < 128) {
      g_out[pb * 128 + tid] = s_out[tid];
    } else if (tid < 192) {
      int m = tid - 128;
      s_out2[m] = packf16(s_out[2*m], s_out[2*m + 1]);
    } else if (tid < 256) {
      s_xh2[tid - 192] = xh_pref;
    }
    __syncthreads();                       // B1

    // prior (tid<256) / encoder (tid>=256), f16 global weight stream
    {
      float4 a4 = {bias_pe, 0.f, 0.f, 0.f};
      if (tid < 256) {
        #pragma unroll
        for (int k8 = 0; k8 < 16; ++k8) {
          uint4 w = Wpr4[k8 * 256 + tid];
          uint4 o = *(const uint4*)&s_out2[k8 * 4];
          dotacc4(w, o, a4);
        }
        float ph = fmaxf(hsum4(a4), 0.f);
        if (tid < 128) { s_mup[tid] = ph; g_mup[pb * 128 + tid] = ph; }
        else {
          float y = expf(ph) + 0.5f;
          float sp = (y > 20.f) ? y : log1pf(expf(y));
          s_sgp[tid - 128] = sp; g_sgp[pb * 128 + tid - 128] = sp;
        }
      } else {
        int j2 = tid - 256;
        #pragma unroll
        for (int k8 = 0; k8 < 16; ++k8) {
          uint4 w = Wen4[k8 * 256 + j2];
          uint4 o = *(const uint4*)&s_out2[k8 * 4];
          dotacc4(w, o, a4);
        }
        #pragma unroll
        for (int k8 = 16; k8 < 32; ++k8) {
          uint4 w = Wen4[k8 * 256 + j2];
          uint4 o = *(const uint4*)&s_xh2[(k8 - 16) * 4];
          dotacc4(w, o, a4);
        }
        float eh = fmaxf(hsum4(a4), 0.f);
        if (j2 < 128) s_ehmu[j2] = eh;
        else { float sq = expf(eh); s_sgq[j2 - 128] = sq; g_sgq[pb * 128 + j2 - 128] = sq; }
      }
    }
    __syncthreads();                       // B2

    // z (f16 into LDS) from prefetched eps + g_muq
    {
      int l = tid & 127;
      float mu = s_ehmu[l] + s_mup[l];
      float sq = s_sgq[l];
      s_z2[tid]       = (_Float16)(mu + sq * e0);
      s_z2[tid + 512] = (_Float16)(mu + sq * e1);
      if (tid < 256) s_z2[tid + 1024] = (_Float16)(mu + sq * e2);
      if (tid < 128) g_muq[pb * 128 + tid] = mu;
    }
    __syncthreads();                       // B3

    // z_hat (W_pz from LDS, conflict-free b128) — thread covers samples {g, g+4, g+8<10}
    {
      int j = tid & 127, g = tid >> 7;
      float4 a0 = {bpz,0,0,0}, a1 = {bpz,0,0,0}, a2 = {bpz,0,0,0};
      #pragma unroll
      for (int k8 = 0; k8 < 16; ++k8) {
        uint4 w = *(const uint4*)&s_wpz[(k8 * 128 + j) * 4];
        uint4 z0 = *(const uint4*)&s_z2[g * 128 + k8 * 8];
        dotacc4(w, z0, a0);
        uint4 z1 = *(const uint4*)&s_z2[(g + 4) * 128 + k8 * 8];
        dotacc4(w, z1, a1);
        if (g < 2) {
          uint4 z2v = *(const uint4*)&s_z2[(g + 8) * 128 + k8 * 8];
          dotacc4(w, z2v, a2);
        }
      }
      s_zh2[g * 128 + j]       = (_Float16)fmaxf(hsum4(a0), 0.f);
      s_zh2[(g + 4) * 128 + j] = (_Float16)fmaxf(hsum4(a1), 0.f);
      if (g < 2)
        s_zh2[(g + 8) * 128 + j] = (_Float16)fmaxf(hsum4(a2), 0.f);
    }
    // gate-x part into register (W_ihx f16 global stream)
    float gbase;
    {
      float4 a4 = {blst, 0.f, 0.f, 0.f};
      #pragma unroll
      for (int k8 = 0; k8 < 16; ++k8) {
        uint4 w = Wihx4[k8 * 512 + tid];
        uint4 xv = *(const uint4*)&s_xh2[k8 * 4];
        dotacc4(w, xv, a4);
      }
      gbase = hsum4(a4);
    }
    __syncthreads();                       // B4

    // gates-z for all 10 samples (persistent register weights)
    for (int s = 0; s < 10; ++s) {
      float4 a4 = {gbase, 0.f, 0.f, 0.f};
      #pragma unroll
      for (int k8 = 0; k8 < 16; ++k8) {
        uint4 zv = *(const uint4*)&s_zh2[s * 128 + k8 * 8];
        dotacc4(wihz[k8], zv, a4);
      }
      s_gz[s * 512 + tid] = hsum4(a4);
    }
    __syncthreads();                       // B5

    // serial LSTM over 10 samples (register W_hh, broadcast h reads)
    for (int s = 0; s < 10; ++s) {
      float4 a4 = {s_gz[s * 512 + tid], 0.f, 0.f, 0.f};
      #pragma unroll
      for (int k8 = 0; k8 < 16; ++k8) {
        uint4 hv = *(const uint4*)&s_h2[k8 * 8];
        dotacc4(whh[k8], hv, a4);
      }
      s_gz[s * 512 + tid] = hsum4(a4);
      __syncthreads();
      if (tid < 128) {
        float gi = s_gz[s * 512 + tid],       gf = s_gz[s * 512 + 128 + tid];
        float gg = s_gz[s * 512 + 256 + tid], go = s_gz[s * 512 + 384 + tid];
        c_reg = sigm(gf) * c_reg + sigm(gi) * tanhf(gg);
        float h = sigm(go) * tanhf(c_reg);
        oacc += h;
        s_h2[tid] = (_Float16)h;
      }
      __syncthreads();
    }
    if (tid < 128) s_out[tid] = oacc * 0.1f;
  }
}

// ---------------- phase 2: ELBO terms, fully parallel ----------------
// Pure-streaming decoder (no big register caches) -> cannot spill at any budget.
__global__ __launch_bounds__(256, 2) void phase2_kernel(
    const float* __restrict__ x, const float* __restrict__ beta_p,
    const float* __restrict__ eps,
    const float* __restrict__ g_out, const float* __restrict__ g_muq, const float* __restrict__ g_sgq,
    const float* __restrict__ g_mup, const float* __restrict__ g_sgp,
    const uint4* __restrict__ Wpz4, const float* __restrict__ b_pz,
    const uint4* __restrict__ Wdez4, const uint4* __restrict__ Wdeo4, const float* __restrict__ b_de,
    double* __restrict__ accum)
{
  __shared__ __align__(16) _Float16 s_z2[5120];
  __shared__ __align__(16) _Float16 s_zh2[5120];
  __shared__ __align__(16) unsigned s_out2[256];
  __shared__ __align__(16) float s_muq[512], s_sgq[512], s_mup[512], s_sgp[512];
  __shared__ float s_wred[4];

  const int tid = threadIdx.x;
  const int p0 = blockIdx.x * 4;        // 4 (t,b) pairs -> 40 sample rows
  const float beta = beta_p[0];
  float acc_loc = 0.f;

  for (int i = tid; i < 512; i += 256) {
    size_t gi = (size_t)p0 * 128 + i;
    s_muq[i] = g_muq[gi]; s_sgq[i] = g_sgq[gi];
    s_mup[i] = g_mup[gi]; s_sgp[i] = g_sgp[gi];
  }
  {
    int pair = tid >> 6, m = tid & 63;
    const float* o = g_out + (size_t)p0 * 128 + pair * 128;
    s_out2[tid] = packf16(o[2*m], o[2*m + 1]);
  }
  __syncthreads();

  // KL + z build ((z-muq)/sq == eps exactly)
  {
    int l = tid & 127;
    int ppb = tid >> 7;
    for (int q = 0; q < 2; ++q) {
      int pp = ppb + 2 * q;
      float mq = s_muq[pp*128 + l], sq = s_sgq[pp*128 + l];
      float mp = s_mup[pp*128 + l], spv = s_sgp[pp*128 + l];
      float inv_sp = 1.f / spv;
      float lsq = __logf(sq), lsp = __logf(spv);
      const float* ep = eps + (size_t)(p0 + pp) * 1280 + l;
      float kl = 0.f;
      #pragma unroll
      for (int s = 0; s < 10; ++s) {
        float e = ep[s * 128];
        float z = mq + sq * e;
        s_z2[(pp * 10 + s) * 128 + l] = (_Float16)z;
        float ap = (z - mp) * inv_sp;
        kl += (-0.5f * e * e - lsq) - (-0.5f * ap * ap - lsp);
      }
      acc_loc -= beta * kl;
    }
  }
  __syncthreads();

  // z_hat: 40 rows, W_pz f16 global stream, 20 rows per thread-group
  {
    int j = tid & 127, grp = tid >> 7;
    float acc[20];
    float bj = b_pz[j];
    #pragma unroll
    for (int u = 0; u < 20; ++u) acc[u] = bj;
    for (int k8 = 0; k8 < 16; ++k8) {
      uint4 w = Wpz4[k8 * 128 + j];
      #pragma unroll
      for (int u = 0; u < 20; ++u) {
        uint4 zv = *(const uint4*)&s_z2[(grp * 20 + u) * 128 + k8 * 8];
        acc[u] = fdot2(w.x, zv.x, acc[u]); acc[u] = fdot2(w.y, zv.y, acc[u]);
        acc[u] = fdot2(w.z, zv.z, acc[u]); acc[u] = fdot2(w.w, zv.w, acc[u]);
      }
    }
    #pragma unroll
    for (int u = 0; u < 20; ++u)
      s_zh2[(grp * 20 + u) * 128 + j] = (_Float16)fmaxf(acc[u], 0.f);
  }
  __syncthreads();

  // decoder + Bernoulli; weights streamed (16 B load per 16-40 fdot2)
  for (int dc = 0; dc < 4; ++dc) {
    int d = tid + 256 * dc;
    if (d < 800) {
      float acco[4] = {0.f, 0.f, 0.f, 0.f};
      #pragma unroll 4
      for (int k8 = 0; k8 < 16; ++k8) {
        uint4 w = Wdeo4[k8 * 800 + d];
        #pragma unroll
        for (int pp = 0; pp < 4; ++pp) {
          uint4 ov = *(const uint4*)&s_out2[pp * 64 + k8 * 4];
          acco[pp] = fdot2(w.x, ov.x, acco[pp]); acco[pp] = fdot2(w.y, ov.y, acco[pp]);
          acco[pp] = fdot2(w.z, ov.z, acco[pp]); acco[pp] = fdot2(w.w, ov.w, acco[pp]);
        }
      }
      float bd = b_de[d];
      for (int pp = 0; pp < 4; ++pp) {
        float acc[10];
        #pragma unroll
        for (int s = 0; s < 10; ++s) acc[s] = 0.f;
        #pragma unroll 4
        for (int k8 = 0; k8 < 16; ++k8) {
          uint4 w = Wdez4[k8 * 800 + d];
          #pragma unroll
          for (int s = 0; s < 10; ++s) {
            uint4 zv = *(const uint4*)&s_zh2[(pp * 10 + s) * 128 + k8 * 8];
            acc[s] = fdot2(w.x, zv.x, acc[s]); acc[s] = fdot2(w.y, zv.y, acc[s]);
            acc[s] = fdot2(w.z, zv.z, acc[s]); acc[s] = fdot2(w.w, zv.w, acc[s]);
          }
        }
        int p = p0 + pp, tt2 = p >> 7, bb = p & 127;
        float xd = x[((size_t)bb * TT + tt2) * 800 + d];
        float base = acco[pp] + bd;
        #pragma unroll
        for (int s = 0; s < 10; ++s) {
          float lg = fmaxf(acc[s] + base, 0.f);
          acc_loc += xd * lg - lg - __logf(1.f + __expf(-lg));
        }
      }
    }
  }

  // block reduction -> one atomic per WG
  float v = acc_loc;
  #pragma unroll
  for (int off = 32; off > 0; off >>= 1) v += __shfl_down(v, off, 64);
  if ((tid & 63) == 0) s_wred[tid >> 6] = v;
  __syncthreads();
  if (tid == 0) {
    double tot = (double)s_wred[0] + (double)s_wred[1] + (double)s_wred[2] + (double)s_wred[3];
    atomicAdd(accum, tot);
  }
}

__global__ void finalize_kernel(const double* __restrict__ accum, float* __restrict__ out) {
  if (threadIdx.x == 0 && blockIdx.x == 0)
    out[0] = (float)(-accum[0] / 122880.0);   // B*T*S
}

// ---------------- host ----------------
extern "C" void kernel_launch(void* const* d_in, const int* in_sizes, int n_in,
                              void* d_out, int out_size, void* d_ws, size_t ws_size,
                              hipStream_t stream) {
  const float* x    = (const float*)d_in[0];
  const float* beta = (const float*)d_in[1];
  const float* eps  = (const float*)d_in[2];
  const float* W_px = (const float*)d_in[3];
  const float* b_px = (const float*)d_in[4];
  const float* W_pz = (const float*)d_in[5];
  const float* b_pz = (const float*)d_in[6];
  const float* W_pr = (const float*)d_in[7];
  const float* b_pr = (const float*)d_in[8];
  const float* W_en = (const float*)d_in[9];
  const float* b_en = (const float*)d_in[10];
  const float* W_de = (const float*)d_in[11];
  const float* b_de = (const float*)d_in[12];
  const float* W_ih = (const float*)d_in[13];
  const float* W_hh = (const float*)d_in[14];
  const float* b_ih = (const float*)d_in[15];
  const float* b_hh = (const float*)d_in[16];
  float* ws = (float*)d_ws;

  // ws offsets (in 4B units)
  constexpr size_t O_WPX  = 0;                      // 102400 fp32
  constexpr size_t O_WPR  = O_WPX  + 102400;        // 16384 uints
  constexpr size_t O_WEN  = O_WPR  + 16384;         // 32768
  constexpr size_t O_WPZ  = O_WEN  + 32768;         // 8192
  constexpr size_t O_WIHX = O_WPZ  + 8192;          // 32768
  constexpr size_t O_WIHZ = O_WIHX + 32768;         // 32768
  constexpr size_t O_WHH  = O_WIHZ + 32768;         // 32768
  constexpr size_t O_WDEZ = O_WHH  + 32768;         // 51200
  constexpr size_t O_WDEO = O_WDEZ + 51200;         // 51200
  constexpr size_t O_BL   = O_WDEO + 51200;         // 512
  constexpr size_t O_ACC  = O_BL   + 512;           // 2 (double)
  constexpr size_t O_XHAT = O_ACC  + 4;             // 786432 uints (f16-packed)
  constexpr size_t O_OUT  = O_XHAT + 1572864;
  constexpr size_t O_MUQ  = O_OUT  + 1572864;
  constexpr size_t O_SGQ  = O_MUQ  + 1572864;
  constexpr size_t O_MUP  = O_SGQ  + 1572864;
  constexpr size_t O_SGP  = O_MUP  + 1572864;
  (void)O_SGP;

  prep_misc<<<dim3(1), dim3(512), 0, stream>>>(b_ih, b_hh, ws + O_BL, (double*)(ws + O_ACC));

  auto pk = [&](const float* src, size_t off, int J, int rs, int k0, int K) {
    int total = J * (K / 2);
    prep_pack_f16<<<dim3((total + 255) / 256), dim3(256), 0, stream>>>(
        src, (unsigned*)(ws + off), J, rs, k0, total);
  };
  pk(W_pr, O_WPR, 256, 128, 0, 128);
  pk(W_en, O_WEN, 256, 256, 0, 256);
  pk(W_pz, O_WPZ, 128, 128, 0, 128);
  pk(W_ih, O_WIHX, 512, 256, 0, 128);
  pk(W_ih, O_WIHZ, 512, 256, 128, 128);
  pk(W_hh, O_WHH, 512, 128, 0, 128);
  pk(W_de, O_WDEZ, 800, 256, 0, 128);
  pk(W_de, O_WDEO, 800, 256, 128, 128);
  prep_transpose<<<dim3((102400 + 255) / 256), dim3(256), 0, stream>>>(
      W_px, ws + O_WPX, 128, 800, 0, 102400);

  xhat_kernel<<<dim3(1536), dim3(256), 0, stream>>>(x, ws + O_WPX, b_px, (unsigned*)(ws + O_XHAT));

  phase1_kernel<<<dim3(128), dim3(512), 0, stream>>>(
      eps, (const unsigned*)(ws + O_XHAT),
      (const uint4*)(ws + O_WPR), b_pr, (const uint4*)(ws + O_WEN), b_en,
      (const uint4*)(ws + O_WPZ), b_pz, (const uint4*)(ws + O_WIHX),
      (const uint4*)(ws + O_WIHZ), (const uint4*)(ws + O_WHH), ws + O_BL,
      ws + O_OUT, ws + O_MUQ, ws + O_SGQ, ws + O_MUP, ws + O_SGP);

  phase2_kernel<<<dim3(3072), dim3(256), 0, stream>>>(
      x, beta, eps, ws + O_OUT, ws + O_MUQ, ws + O_SGQ, ws + O_MUP, ws + O_SGP,
      (const uint4*)(ws + O_WPZ), b_pz,
      (const uint4*)(ws + O_WDEZ), (const uint4*)(ws + O_WDEO), b_de,
      (double*)(ws + O_ACC));

  finalize_kernel<<<dim3(1), dim3(64), 0, stream>>>((const double*)(ws + O_ACC), (float*)d_out);
}

// Round 7
// 2198.745 us; speedup vs baseline: 3.4020x; 2.2658x over previous
//
#include <hip/hip_runtime.h>
#include <math.h>

#define TT 96
#define BB 128
#define DD 800
#define LL 128

typedef _Float16 h2v __attribute__((ext_vector_type(2)));

__device__ __forceinline__ h2v u2h(unsigned u) {
  union { unsigned u; h2v h; } x; x.u = u; return x.h;
}
__device__ __forceinline__ float fdot2(unsigned w, unsigned v, float acc) {
  return __builtin_amdgcn_fdot2(u2h(w), u2h(v), acc, false);
}
__device__ __forceinline__ unsigned packf16(float a, float b) {
  union { _Float16 h[2]; unsigned u; } x;
  x.h[0] = (_Float16)a; x.h[1] = (_Float16)b;
  return x.u;
}
__device__ __forceinline__ float sigm(float x) { return 1.f/(1.f + __expf(-x)); }
__device__ __forceinline__ float hsum4(float4 a) { return (a.x + a.y) + (a.z + a.w); }

__device__ __forceinline__ void dotacc4(uint4 wv, uint4 vv, float4& av) {
  av.x = fdot2(wv.x, vv.x, av.x);
  av.y = fdot2(wv.y, vv.y, av.y);
  av.z = fdot2(wv.z, vv.z, av.z);
  av.w = fdot2(wv.w, vv.w, av.w);
}

// ---------------- prep ----------------
__global__ void prep_misc(const float* __restrict__ b_ih, const float* __restrict__ b_hh,
                          float* __restrict__ b_lstm, double* __restrict__ accum) {
  int t = threadIdx.x;
  if (t < 512) b_lstm[t] = b_ih[t] + b_hh[t];
  if (t == 0) accum[0] = 0.0;
}

// f16 interleaved pack: dst[((k>>3)*J + j)*4 + ((k>>1)&3)] = pack(src[j*rs+k0+k], src[j*rs+k0+k+1])
__global__ void prep_pack_f16(const float* __restrict__ src, unsigned* __restrict__ dst,
                              int J, int rs, int k0, int total) {
  int idx = blockIdx.x * 256 + threadIdx.x;
  if (idx >= total) return;
  int u = idx & 3;
  int t2 = idx >> 2;
  int k8 = t2 / J;
  int j = t2 - k8 * J;
  int k = k8 * 8 + u * 2;
  const float* r = src + (size_t)j * rs + k0 + k;
  dst[idx] = packf16(r[0], r[1]);
}

// fp32 interleaved transpose (for W_px)
__global__ void prep_transpose(const float* __restrict__ src, float* __restrict__ dst,
                               int J, int rs, int k0, int total) {
  int idx = blockIdx.x * 256 + threadIdx.x;
  if (idx >= total) return;
  int J4 = J * 4;
  int k4 = idx / J4;
  int rem = idx - k4 * J4;
  int j = rem >> 2;
  int kk = rem & 3;
  dst[idx] = src[j * rs + k0 + k4 * 4 + kk];
}

// ---------------- phase 0: x_hat (emits f16-packed pairs) ----------------
__device__ __forceinline__ float dot4(float4 w, float4 v) {
  return w.x*v.x + w.y*v.y + w.z*v.z + w.w*v.w;
}
__global__ __launch_bounds__(256) void xhat_kernel(const float* __restrict__ x,
                                                   const float* __restrict__ Wpx4,
                                                   const float* __restrict__ b_px,
                                                   unsigned* __restrict__ xhat2) {
  __shared__ __align__(16) float sx[8][800];
  const int wg = blockIdx.x, tid = threadIdx.x;
  const int p0 = wg * 8;
  for (int r = 0; r < 8; ++r) {
    int p = p0 + r; int t = p >> 7; int b = p & 127;
    const float* row = x + ((size_t)b * TT + t) * 800;
    for (int col = tid; col < 800; col += 256) sx[r][col] = row[col];
  }
  __syncthreads();
  const int j = tid & 127, g = tid >> 7;
  float acc[4];
  const float bj = b_px[j];
  #pragma unroll
  for (int u = 0; u < 4; ++u) acc[u] = bj;
  const float4* W = (const float4*)Wpx4;
  #pragma unroll 2
  for (int k4 = 0; k4 < 200; ++k4) {
    float4 w = W[k4 * 128 + j];
    #pragma unroll
    for (int u = 0; u < 4; ++u) {
      float4 xv = *(const float4*)&sx[g + 2*u][k4 * 4];
      acc[u] += dot4(w, xv);
    }
  }
  #pragma unroll
  for (int u = 0; u < 4; ++u) {
    float v = fmaxf(acc[u], 0.f);
    float vp = __shfl_xor(v, 1, 64);    // partner lane j^1 (same wave)
    if ((j & 1) == 0) {
      int p = p0 + g + 2*u;
      xhat2[(size_t)p * 64 + (j >> 1)] = packf16(v, vp);
    }
  }
}

// ---------------- phase 1: sequential scan, one WG (512 thr) per batch chain ----------------
// Designed for the allocator's hard 128-VGPR budget at 512 threads (measured r3/r4/r6):
// NO persistent register weight arrays. All feed-forward weights are streamed from
// global (L2-resident, latency hidden by 8 waves); whh[16] (64 VGPRs) is reloaded
// fresh EACH TIMESTEP right before the serial loop, so its live range spans only
// the low-pressure serial section. Barriers fence the loads in place.
__global__ __launch_bounds__(512) void phase1_kernel(
    const float* __restrict__ eps, const unsigned* __restrict__ xhat2g,
    const uint4* __restrict__ Wpr4, const float* __restrict__ b_pr,
    const uint4* __restrict__ Wen4, const float* __restrict__ b_en,
    const uint4* __restrict__ Wpz4, const float* __restrict__ b_pz,
    const uint4* __restrict__ Wihx4, const uint4* __restrict__ Wihz4,
    const uint4* __restrict__ Whh4, const float* __restrict__ b_lstm,
    float* __restrict__ g_out, float* __restrict__ g_muq, float* __restrict__ g_sgq,
    float* __restrict__ g_mup, float* __restrict__ g_sgp)
{
  __shared__ __align__(16) unsigned s_wpz[8192];   // W_pz f16, LDS-resident (32 KB)
  __shared__ __align__(16) float s_gz[5120];       // gates per sample [10][512]
  __shared__ __align__(16) _Float16 s_z2[1280];
  __shared__ __align__(16) _Float16 s_zh2[1280];
  __shared__ __align__(16) float s_out[128];
  __shared__ __align__(16) float s_ehmu[128];
  __shared__ __align__(16) float s_mup[128];
  __shared__ __align__(16) float s_sgp[128];
  __shared__ __align__(16) float s_sgq[128];
  __shared__ __align__(16) unsigned s_out2[64];
  __shared__ __align__(16) unsigned s_xh2[64];
  __shared__ __align__(16) _Float16 s_h2[128];

  const int tid = threadIdx.x;
  const int b = blockIdx.x;

  for (int i = tid; i < 8192; i += 512) s_wpz[i] = ((const unsigned*)Wpz4)[i];
  if (tid < 128) { s_out[tid] = 0.f; s_h2[tid] = (_Float16)0.f; }
  float c_reg = 0.f;
  const float blst = b_lstm[tid];
  const float bias_pe = (tid < 256) ? b_pr[tid] : b_en[tid - 256];
  const float bpz = b_pz[tid & 127];

  for (int t = 0; t < TT; ++t) {
    const size_t pb = (size_t)t * BB + b;
    const float* epsb = eps + pb * 1280;
    // prefetch globals for this timestep (no barrier dependence)
    unsigned xh_pref = 0;
    if (tid >= 192 && tid < 256) xh_pref = xhat2g[pb * 64 + (tid - 192)];
    float e0 = epsb[tid];
    float e1 = epsb[tid + 512];
    float e2 = (tid < 256) ? epsb[tid + 1024] : 0.f;

    __syncthreads();                       // B0: prev-timestep s_out/s_h2 visible
    float oacc = 0.f;
    if (tid < 128) {
      g_out[pb * 128 + tid] = s_out[tid];
    } else if (tid < 192) {
      int m = tid - 128;
      s_out2[m] = packf16(s_out[2*m], s_out[2*m + 1]);
    } else if (tid < 256) {
      s_xh2[tid - 192] = xh_pref;
    }
    __syncthreads();                       // B1

    // prior (tid<256) / encoder (tid>=256), f16 global weight stream (unroll-limited)
    {
      float4 a4 = {bias_pe, 0.f, 0.f, 0.f};
      if (tid < 256) {
        #pragma unroll 4
        for (int k8 = 0; k8 < 16; ++k8) {
          uint4 w = Wpr4[k8 * 256 + tid];
          uint4 o = *(const uint4*)&s_out2[k8 * 4];
          dotacc4(w, o, a4);
        }
        float ph = fmaxf(hsum4(a4), 0.f);
        if (tid < 128) { s_mup[tid] = ph; g_mup[pb * 128 + tid] = ph; }
        else {
          float y = expf(ph) + 0.5f;
          float sp = (y > 20.f) ? y : log1pf(expf(y));
          s_sgp[tid - 128] = sp; g_sgp[pb * 128 + tid - 128] = sp;
        }
      } else {
        int j2 = tid - 256;
        #pragma unroll 4
        for (int k8 = 0; k8 < 16; ++k8) {
          uint4 w = Wen4[k8 * 256 + j2];
          uint4 o = *(const uint4*)&s_out2[k8 * 4];
          dotacc4(w, o, a4);
        }
        #pragma unroll 4
        for (int k8 = 16; k8 < 32; ++k8) {
          uint4 w = Wen4[k8 * 256 + j2];
          uint4 o = *(const uint4*)&s_xh2[(k8 - 16) * 4];
          dotacc4(w, o, a4);
        }
        float eh = fmaxf(hsum4(a4), 0.f);
        if (j2 < 128) s_ehmu[j2] = eh;
        else { float sq = expf(eh); s_sgq[j2 - 128] = sq; g_sgq[pb * 128 + j2 - 128] = sq; }
      }
    }
    __syncthreads();                       // B2

    // z (f16 into LDS) from prefetched eps + g_muq
    {
      int l = tid & 127;
      float mu = s_ehmu[l] + s_mup[l];
      float sq = s_sgq[l];
      s_z2[tid]       = (_Float16)(mu + sq * e0);
      s_z2[tid + 512] = (_Float16)(mu + sq * e1);
      if (tid < 256) s_z2[tid + 1024] = (_Float16)(mu + sq * e2);
      if (tid < 128) g_muq[pb * 128 + tid] = mu;
    }
    __syncthreads();                       // B3

    // z_hat (W_pz from LDS, conflict-free b128) — thread covers samples {g, g+4, g+8<10}
    {
      int j = tid & 127, g = tid >> 7;
      float4 a0 = {bpz,0,0,0}, a1 = {bpz,0,0,0}, a2 = {bpz,0,0,0};
      #pragma unroll 4
      for (int k8 = 0; k8 < 16; ++k8) {
        uint4 w = *(const uint4*)&s_wpz[(k8 * 128 + j) * 4];
        uint4 z0 = *(const uint4*)&s_z2[g * 128 + k8 * 8];
        dotacc4(w, z0, a0);
        uint4 z1 = *(const uint4*)&s_z2[(g + 4) * 128 + k8 * 8];
        dotacc4(w, z1, a1);
        if (g < 2) {
          uint4 z2v = *(const uint4*)&s_z2[(g + 8) * 128 + k8 * 8];
          dotacc4(w, z2v, a2);
        }
      }
      s_zh2[g * 128 + j]       = (_Float16)fmaxf(hsum4(a0), 0.f);
      s_zh2[(g + 4) * 128 + j] = (_Float16)fmaxf(hsum4(a1), 0.f);
      if (g < 2)
        s_zh2[(g + 8) * 128 + j] = (_Float16)fmaxf(hsum4(a2), 0.f);
    }
    // gate-x part into register (W_ihx f16 global stream)
    float gbase;
    {
      float4 a4 = {blst, 0.f, 0.f, 0.f};
      #pragma unroll 4
      for (int k8 = 0; k8 < 16; ++k8) {
        uint4 w = Wihx4[k8 * 512 + tid];
        uint4 xv = *(const uint4*)&s_xh2[k8 * 4];
        dotacc4(w, xv, a4);
      }
      gbase = hsum4(a4);
    }
    __syncthreads();                       // B4

    // gates-z for all 10 samples; W_ihz STREAMED (2 passes x 5 samples)
    #pragma unroll
    for (int half = 0; half < 2; ++half) {
      float4 a5[5];
      #pragma unroll
      for (int s = 0; s < 5; ++s) a5[s] = float4{gbase, 0.f, 0.f, 0.f};
      #pragma unroll 4
      for (int k8 = 0; k8 < 16; ++k8) {
        uint4 w = Wihz4[k8 * 512 + tid];
        #pragma unroll
        for (int s = 0; s < 5; ++s) {
          uint4 zv = *(const uint4*)&s_zh2[(half * 5 + s) * 128 + k8 * 8];
          dotacc4(w, zv, a5[s]);
        }
      }
      #pragma unroll
      for (int s = 0; s < 5; ++s)
        s_gz[(half * 5 + s) * 512 + tid] = hsum4(a5[s]);
    }

    // Rematerialize W_hh row for THIS timestep only (64 VGPRs, live range =
    // serial section only; B5 fences it from the streaming segments above).
    uint4 whh[16];
    #pragma unroll
    for (int k8 = 0; k8 < 16; ++k8) whh[k8] = Whh4[k8 * 512 + tid];
    __syncthreads();                       // B5

    // serial LSTM over 10 samples (register W_hh, broadcast h reads)
    for (int s = 0; s < 10; ++s) {
      float4 a4 = {s_gz[s * 512 + tid], 0.f, 0.f, 0.f};
      #pragma unroll
      for (int k8 = 0; k8 < 16; ++k8) {
        uint4 hv = *(const uint4*)&s_h2[k8 * 8];
        dotacc4(whh[k8], hv, a4);
      }
      s_gz[s * 512 + tid] = hsum4(a4);
      __syncthreads();
      if (tid < 128) {
        float gi = s_gz[s * 512 + tid],       gf = s_gz[s * 512 + 128 + tid];
        float gg = s_gz[s * 512 + 256 + tid], go = s_gz[s * 512 + 384 + tid];
        c_reg = sigm(gf) * c_reg + sigm(gi) * tanhf(gg);
        float h = sigm(go) * tanhf(c_reg);
        oacc += h;
        s_h2[tid] = (_Float16)h;
      }
      __syncthreads();
    }
    if (tid < 128) s_out[tid] = oacc * 0.1f;
  }
}

// ---------------- phase 2: ELBO terms, fully parallel ----------------
// Pure-streaming decoder (no big register caches) -> cannot spill at any budget.
__global__ __launch_bounds__(256, 2) void phase2_kernel(
    const float* __restrict__ x, const float* __restrict__ beta_p,
    const float* __restrict__ eps,
    const float* __restrict__ g_out, const float* __restrict__ g_muq, const float* __restrict__ g_sgq,
    const float* __restrict__ g_mup, const float* __restrict__ g_sgp,
    const uint4* __restrict__ Wpz4, const float* __restrict__ b_pz,
    const uint4* __restrict__ Wdez4, const uint4* __restrict__ Wdeo4, const float* __restrict__ b_de,
    double* __restrict__ accum)
{
  __shared__ __align__(16) _Float16 s_z2[5120];
  __shared__ __align__(16) _Float16 s_zh2[5120];
  __shared__ __align__(16) unsigned s_out2[256];
  __shared__ __align__(16) float s_muq[512], s_sgq[512], s_mup[512], s_sgp[512];
  __shared__ float s_wred[4];

  const int tid = threadIdx.x;
  const int p0 = blockIdx.x * 4;        // 4 (t,b) pairs -> 40 sample rows
  const float beta = beta_p[0];
  float acc_loc = 0.f;

  for (int i = tid; i < 512; i += 256) {
    size_t gi = (size_t)p0 * 128 + i;
    s_muq[i] = g_muq[gi]; s_sgq[i] = g_sgq[gi];
    s_mup[i] = g_mup[gi]; s_sgp[i] = g_sgp[gi];
  }
  {
    int pair = tid >> 6, m = tid & 63;
    const float* o = g_out + (size_t)p0 * 128 + pair * 128;
    s_out2[tid] = packf16(o[2*m], o[2*m + 1]);
  }
  __syncthreads();

  // KL + z build ((z-muq)/sq == eps exactly)
  {
    int l = tid & 127;
    int ppb = tid >> 7;
    for (int q = 0; q < 2; ++q) {
      int pp = ppb + 2 * q;
      float mq = s_muq[pp*128 + l], sq = s_sgq[pp*128 + l];
      float mp = s_mup[pp*128 + l], spv = s_sgp[pp*128 + l];
      float inv_sp = 1.f / spv;
      float lsq = __logf(sq), lsp = __logf(spv);
      const float* ep = eps + (size_t)(p0 + pp) * 1280 + l;
      float kl = 0.f;
      #pragma unroll
      for (int s = 0; s < 10; ++s) {
        float e = ep[s * 128];
        float z = mq + sq * e;
        s_z2[(pp * 10 + s) * 128 + l] = (_Float16)z;
        float ap = (z - mp) * inv_sp;
        kl += (-0.5f * e * e - lsq) - (-0.5f * ap * ap - lsp);
      }
      acc_loc -= beta * kl;
    }
  }
  __syncthreads();

  // z_hat: 40 rows, W_pz f16 global stream, 20 rows per thread-group
  {
    int j = tid & 127, grp = tid >> 7;
    float acc[20];
    float bj = b_pz[j];
    #pragma unroll
    for (int u = 0; u < 20; ++u) acc[u] = bj;
    for (int k8 = 0; k8 < 16; ++k8) {
      uint4 w = Wpz4[k8 * 128 + j];
      #pragma unroll
      for (int u = 0; u < 20; ++u) {
        uint4 zv = *(const uint4*)&s_z2[(grp * 20 + u) * 128 + k8 * 8];
        acc[u] = fdot2(w.x, zv.x, acc[u]); acc[u] = fdot2(w.y, zv.y, acc[u]);
        acc[u] = fdot2(w.z, zv.z, acc[u]); acc[u] = fdot2(w.w, zv.w, acc[u]);
      }
    }
    #pragma unroll
    for (int u = 0; u < 20; ++u)
      s_zh2[(grp * 20 + u) * 128 + j] = (_Float16)fmaxf(acc[u], 0.f);
  }
  __syncthreads();

  // decoder + Bernoulli; weights streamed (16 B load per 16-40 fdot2)
  for (int dc = 0; dc < 4; ++dc) {
    int d = tid + 256 * dc;
    if (d < 800) {
      float acco[4] = {0.f, 0.f, 0.f, 0.f};
      #pragma unroll 4
      for (int k8 = 0; k8 < 16; ++k8) {
        uint4 w = Wdeo4[k8 * 800 + d];
        #pragma unroll
        for (int pp = 0; pp < 4; ++pp) {
          uint4 ov = *(const uint4*)&s_out2[pp * 64 + k8 * 4];
          acco[pp] = fdot2(w.x, ov.x, acco[pp]); acco[pp] = fdot2(w.y, ov.y, acco[pp]);
          acco[pp] = fdot2(w.z, ov.z, acco[pp]); acco[pp] = fdot2(w.w, ov.w, acco[pp]);
        }
      }
      float bd = b_de[d];
      for (int pp = 0; pp < 4; ++pp) {
        float acc[10];
        #pragma unroll
        for (int s = 0; s < 10; ++s) acc[s] = 0.f;
        #pragma unroll 4
        for (int k8 = 0; k8 < 16; ++k8) {
          uint4 w = Wdez4[k8 * 800 + d];
          #pragma unroll
          for (int s = 0; s < 10; ++s) {
            uint4 zv = *(const uint4*)&s_zh2[(pp * 10 + s) * 128 + k8 * 8];
            acc[s] = fdot2(w.x, zv.x, acc[s]); acc[s] = fdot2(w.y, zv.y, acc[s]);
            acc[s] = fdot2(w.z, zv.z, acc[s]); acc[s] = fdot2(w.w, zv.w, acc[s]);
          }
        }
        int p = p0 + pp, tt2 = p >> 7, bb = p & 127;
        float xd = x[((size_t)bb * TT + tt2) * 800 + d];
        float base = acco[pp] + bd;
        #pragma unroll
        for (int s = 0; s < 10; ++s) {
          float lg = fmaxf(acc[s] + base, 0.f);
          acc_loc += xd * lg - lg - __logf(1.f + __expf(-lg));
        }
      }
    }
  }

  // block reduction -> one atomic per WG
  float v = acc_loc;
  #pragma unroll
  for (int off = 32; off > 0; off >>= 1) v += __shfl_down(v, off, 64);
  if ((tid & 63) == 0) s_wred[tid >> 6] = v;
  __syncthreads();
  if (tid == 0) {
    double tot = (double)s_wred[0] + (double)s_wred[1] + (double)s_wred[2] + (double)s_wred[3];
    atomicAdd(accum, tot);
  }
}

__global__ void finalize_kernel(const double* __restrict__ accum, float* __restrict__ out) {
  if (threadIdx.x == 0 && blockIdx.x == 0)
    out[0] = (float)(-accum[0] / 122880.0);   // B*T*S
}

// ---------------- host ----------------
extern "C" void kernel_launch(void* const* d_in, const int* in_sizes, int n_in,
                              void* d_out, int out_size, void* d_ws, size_t ws_size,
                              hipStream_t stream) {
  const float* x    = (const float*)d_in[0];
  const float* beta = (const float*)d_in[1];
  const float* eps  = (const float*)d_in[2];
  const float* W_px = (const float*)d_in[3];
  const float* b_px = (const float*)d_in[4];
  const float* W_pz = (const float*)d_in[5];
  const float* b_pz = (const float*)d_in[6];
  const float* W_pr = (const float*)d_in[7];
  const float* b_pr = (const float*)d_in[8];
  const float* W_en = (const float*)d_in[9];
  const float* b_en = (const float*)d_in[10];
  const float* W_de = (const float*)d_in[11];
  const float* b_de = (const float*)d_in[12];
  const float* W_ih = (const float*)d_in[13];
  const float* W_hh = (const float*)d_in[14];
  const float* b_ih = (const float*)d_in[15];
  const float* b_hh = (const float*)d_in[16];
  float* ws = (float*)d_ws;

  // ws offsets (in 4B units)
  constexpr size_t O_WPX  = 0;                      // 102400 fp32
  constexpr size_t O_WPR  = O_WPX  + 102400;        // 16384 uints
  constexpr size_t O_WEN  = O_WPR  + 16384;         // 32768
  constexpr size_t O_WPZ  = O_WEN  + 32768;         // 8192
  constexpr size_t O_WIHX = O_WPZ  + 8192;          // 32768
  constexpr size_t O_WIHZ = O_WIHX + 32768;         // 32768
  constexpr size_t O_WHH  = O_WIHZ + 32768;         // 32768
  constexpr size_t O_WDEZ = O_WHH  + 32768;         // 51200
  constexpr size_t O_WDEO = O_WDEZ + 51200;         // 51200
  constexpr size_t O_BL   = O_WDEO + 51200;         // 512
  constexpr size_t O_ACC  = O_BL   + 512;           // 2 (double)
  constexpr size_t O_XHAT = O_ACC  + 4;             // 786432 uints (f16-packed)
  constexpr size_t O_OUT  = O_XHAT + 1572864;
  constexpr size_t O_MUQ  = O_OUT  + 1572864;
  constexpr size_t O_SGQ  = O_MUQ  + 1572864;
  constexpr size_t O_MUP  = O_SGQ  + 1572864;
  constexpr size_t O_SGP  = O_MUP  + 1572864;
  (void)O_SGP;

  prep_misc<<<dim3(1), dim3(512), 0, stream>>>(b_ih, b_hh, ws + O_BL, (double*)(ws + O_ACC));

  auto pk = [&](const float* src, size_t off, int J, int rs, int k0, int K) {
    int total = J * (K / 2);
    prep_pack_f16<<<dim3((total + 255) / 256), dim3(256), 0, stream>>>(
        src, (unsigned*)(ws + off), J, rs, k0, total);
  };
  pk(W_pr, O_WPR, 256, 128, 0, 128);
  pk(W_en, O_WEN, 256, 256, 0, 256);
  pk(W_pz, O_WPZ, 128, 128, 0, 128);
  pk(W_ih, O_WIHX, 512, 256, 0, 128);
  pk(W_ih, O_WIHZ, 512, 256, 128, 128);
  pk(W_hh, O_WHH, 512, 128, 0, 128);
  pk(W_de, O_WDEZ, 800, 256, 0, 128);
  pk(W_de, O_WDEO, 800, 256, 128, 128);
  prep_transpose<<<dim3((102400 + 255) / 256), dim3(256), 0, stream>>>(
      W_px, ws + O_WPX, 128, 800, 0, 102400);

  xhat_kernel<<<dim3(1536), dim3(256), 0, stream>>>(x, ws + O_WPX, b_px, (unsigned*)(ws + O_XHAT));

  phase1_kernel<<<dim3(128), dim3(512), 0, stream>>>(
      eps, (const unsigned*)(ws + O_XHAT),
      (const uint4*)(ws + O_WPR), b_pr, (const uint4*)(ws + O_WEN), b_en,
      (const uint4*)(ws + O_WPZ), b_pz, (const uint4*)(ws + O_WIHX),
      (const uint4*)(ws + O_WIHZ), (const uint4*)(ws + O_WHH), ws + O_BL,
      ws + O_OUT, ws + O_MUQ, ws + O_SGQ, ws + O_MUP, ws + O_SGP);

  phase2_kernel<<<dim3(3072), dim3(256), 0, stream>>>(
      x, beta, eps, ws + O_OUT, ws + O_MUQ, ws + O_SGQ, ws + O_MUP, ws + O_SGP,
      (const uint4*)(ws + O_WPZ), b_pz,
      (const uint4*)(ws + O_WDEZ), (const uint4*)(ws + O_WDEO), b_de,
      (double*)(ws + O_ACC));

  finalize_kernel<<<dim3(1), dim3(64), 0, stream>>>((const double*)(ws + O_ACC), (float*)d_out);
}

// Round 8
// 1684.345 us; speedup vs baseline: 4.4409x; 1.3054x over previous
//
#include <hip/hip_runtime.h>
#include <math.h>

#define TT 96
#define BB 128
#define DD 800
#define LL 128

typedef _Float16 h2v __attribute__((ext_vector_type(2)));
typedef _Float16 f16x8 __attribute__((ext_vector_type(8)));
typedef float f32x4 __attribute__((ext_vector_type(4)));

__device__ __forceinline__ h2v u2h(unsigned u) {
  union { unsigned u; h2v h; } x; x.u = u; return x.h;
}
__device__ __forceinline__ float fdot2(unsigned w, unsigned v, float acc) {
  return __builtin_amdgcn_fdot2(u2h(w), u2h(v), acc, false);
}
__device__ __forceinline__ unsigned packf16(float a, float b) {
  union { _Float16 h[2]; unsigned u; } x;
  x.h[0] = (_Float16)a; x.h[1] = (_Float16)b;
  return x.u;
}
__device__ __forceinline__ f16x8 u4h8(uint4 u) {
  union { uint4 u; f16x8 h; } x; x.u = u; return x.h;
}
__device__ __forceinline__ f32x4 mfma16(uint4 a, uint4 b, f32x4 c) {
  return __builtin_amdgcn_mfma_f32_16x16x32_f16(u4h8(a), u4h8(b), c, 0, 0, 0);
}
__device__ __forceinline__ float sigm(float x) { return 1.f/(1.f + __expf(-x)); }
__device__ __forceinline__ float hsum4(float4 a) { return (a.x + a.y) + (a.z + a.w); }

__device__ __forceinline__ void dotacc4(uint4 wv, uint4 vv, float4& av) {
  av.x = fdot2(wv.x, vv.x, av.x);
  av.y = fdot2(wv.y, vv.y, av.y);
  av.z = fdot2(wv.z, vv.z, av.z);
  av.w = fdot2(wv.w, vv.w, av.w);
}

// ---------------- prep ----------------
__global__ void prep_misc(const float* __restrict__ b_ih, const float* __restrict__ b_hh,
                          float* __restrict__ b_lstm, double* __restrict__ accum) {
  int t = threadIdx.x;
  if (t < 512) b_lstm[t] = b_ih[t] + b_hh[t];
  if (t == 0) accum[0] = 0.0;
}

// f16 interleaved pack (fdot2 layout)
__global__ void prep_pack_f16(const float* __restrict__ src, unsigned* __restrict__ dst,
                              int J, int rs, int k0, int total) {
  int idx = blockIdx.x * 256 + threadIdx.x;
  if (idx >= total) return;
  int u = idx & 3;
  int t2 = idx >> 2;
  int k8 = t2 / J;
  int j = t2 - k8 * J;
  int k = k8 * 8 + u * 2;
  const float* r = src + (size_t)j * rs + k0 + k;
  dst[idx] = packf16(r[0], r[1]);
}

// MFMA B-fragment layout pack: B = W^T; lane holds B[k][n] with n-part = lane&15,
// k = ks*32 + (lane>>4)*8 + j. g indexes 16-col tiles:
//  mode0 (N=512, gates): n = 128*(g&3) + 16*(g>>2) + (lane&15)   [g = wave*4 + gate]
//  mode1 (N=128):        n = 16*g + (lane&15)
__global__ void prep_bfrag(const float* __restrict__ src, unsigned* __restrict__ dst,
                           int rs, int k0, int KS, int mode, int total) {
  int idx = blockIdx.x * 256 + threadIdx.x;
  if (idx >= total) return;
  int jj = idx & 3;
  int lane = (idx >> 2) & 63;
  int t2 = idx >> 8;
  int ks = t2 % KS;
  int g = t2 / KS;
  int n = (mode == 0) ? (128 * (g & 3) + 16 * (g >> 2) + (lane & 15))
                      : (16 * g + (lane & 15));
  int k = ks * 32 + (lane >> 4) * 8 + jj * 2;
  const float* r = src + (size_t)n * rs + k0 + k;
  dst[idx] = packf16(r[0], r[1]);
}

// fp32 interleaved transpose (for W_px)
__global__ void prep_transpose(const float* __restrict__ src, float* __restrict__ dst,
                               int J, int rs, int k0, int total) {
  int idx = blockIdx.x * 256 + threadIdx.x;
  if (idx >= total) return;
  int J4 = J * 4;
  int k4 = idx / J4;
  int rem = idx - k4 * J4;
  int j = rem >> 2;
  int kk = rem & 3;
  dst[idx] = src[j * rs + k0 + k4 * 4 + kk];
}

// ---------------- phase 0: x_hat (emits f16-packed pairs) ----------------
__device__ __forceinline__ float dot4(float4 w, float4 v) {
  return w.x*v.x + w.y*v.y + w.z*v.z + w.w*v.w;
}
__global__ __launch_bounds__(256) void xhat_kernel(const float* __restrict__ x,
                                                   const float* __restrict__ Wpx4,
                                                   const float* __restrict__ b_px,
                                                   unsigned* __restrict__ xhat2) {
  __shared__ __align__(16) float sx[8][800];
  const int wg = blockIdx.x, tid = threadIdx.x;
  const int p0 = wg * 8;
  for (int r = 0; r < 8; ++r) {
    int p = p0 + r; int t = p >> 7; int b = p & 127;
    const float* row = x + ((size_t)b * TT + t) * 800;
    for (int col = tid; col < 800; col += 256) sx[r][col] = row[col];
  }
  __syncthreads();
  const int j = tid & 127, g = tid >> 7;
  float acc[4];
  const float bj = b_px[j];
  #pragma unroll
  for (int u = 0; u < 4; ++u) acc[u] = bj;
  const float4* W = (const float4*)Wpx4;
  #pragma unroll 2
  for (int k4 = 0; k4 < 200; ++k4) {
    float4 w = W[k4 * 128 + j];
    #pragma unroll
    for (int u = 0; u < 4; ++u) {
      float4 xv = *(const float4*)&sx[g + 2*u][k4 * 4];
      acc[u] += dot4(w, xv);
    }
  }
  #pragma unroll
  for (int u = 0; u < 4; ++u) {
    float v = fmaxf(acc[u], 0.f);
    float vp = __shfl_xor(v, 1, 64);
    if ((j & 1) == 0) {
      int p = p0 + g + 2*u;
      xhat2[(size_t)p * 64 + (j >> 1)] = packf16(v, vp);
    }
  }
}

// ---------------- phase 1: sequential scan, MFMA inner tiles ----------------
// LDS-inst bound before (≈3400 ds_read_b128/timestep/CU). MFMA tiles cut that ~4x:
// z_hat / gates-z / serial-LSTM run as 16x16x32 f16 MFMAs (M=samples, N=cols).
// Wave w owns h-indices [16w,16w+16): its 4 N-tiles are the 4 gates at those
// columns, so the LSTM nonlinearity is wave-local. Weights stream from L2 in
// B-frag layout; whh frags (64 VGPR) rematerialized per timestep (no spill at
// the 128-VGPR/512-thread budget - r7 evidence).
__global__ __launch_bounds__(512) void phase1_kernel(
    const float* __restrict__ eps, const unsigned* __restrict__ xhat2g,
    const uint4* __restrict__ Wpr4, const float* __restrict__ b_pr,
    const uint4* __restrict__ Wen4, const float* __restrict__ b_en,
    const uint4* __restrict__ BFpz, const float* __restrict__ b_pz,
    const uint4* __restrict__ Wihx4, const uint4* __restrict__ BFihz,
    const uint4* __restrict__ BFhh, const float* __restrict__ b_lstm,
    float* __restrict__ g_out, float* __restrict__ g_muq, float* __restrict__ g_sgq,
    float* __restrict__ g_mup, float* __restrict__ g_sgp)
{
  __shared__ __align__(16) float s_gz[5120];        // [10][512] gate pre-acts
  __shared__ __align__(16) _Float16 s_z2[16*136];   // padded rows (stride 136)
  __shared__ __align__(16) _Float16 s_zh2[16*136];
  __shared__ __align__(16) float s_gxh[512];
  __shared__ __align__(16) float s_out[128];
  __shared__ __align__(16) float s_ehmu[128];
  __shared__ __align__(16) float s_mup[128];
  __shared__ __align__(16) float s_sgp[128];
  __shared__ __align__(16) float s_sgq[128];
  __shared__ __align__(16) unsigned s_out2[64];
  __shared__ __align__(16) unsigned s_xh2[64];
  __shared__ __align__(16) _Float16 s_h2[128];

  const int tid = threadIdx.x;
  const int b = blockIdx.x;
  const int wv = tid >> 6;
  const int lane = tid & 63;
  const int l15 = lane & 15;
  const int quad = lane >> 4;

  if (tid < 128) { s_out[tid] = 0.f; s_h2[tid] = (_Float16)0.f; }
  float c_reg = 0.f;                       // lanes<16: cell state for h-idx 16*wv+lane
  const float blst = b_lstm[tid];
  const float bias_pe = (tid < 256) ? b_pr[tid] : b_en[tid - 256];
  const float bz = b_pz[16 * wv + l15];

  for (int t = 0; t < TT; ++t) {
    const size_t pb = (size_t)t * BB + b;
    const float* epsb = eps + pb * 1280;
    unsigned xh_pref = 0;
    if (tid >= 192 && tid < 256) xh_pref = xhat2g[pb * 64 + (tid - 192)];
    float e0 = epsb[tid];
    float e1 = epsb[tid + 512];
    float e2 = (tid < 256) ? epsb[tid + 1024] : 0.f;

    __syncthreads();                       // B0: prev s_out/s_h2 visible
    float oacc = 0.f;
    if (tid < 128) {
      g_out[pb * 128 + tid] = s_out[tid];
    } else if (tid < 192) {
      int m = tid - 128;
      s_out2[m] = packf16(s_out[2*m], s_out[2*m + 1]);
    } else if (tid < 256) {
      s_xh2[tid - 192] = xh_pref;
    }
    __syncthreads();                       // B1

    // prior (tid<256) / encoder (tid>=256): fdot2, weights streamed from global
    {
      float4 a4 = {bias_pe, 0.f, 0.f, 0.f};
      if (tid < 256) {
        #pragma unroll 4
        for (int k8 = 0; k8 < 16; ++k8) {
          uint4 w = Wpr4[k8 * 256 + tid];
          uint4 o = *(const uint4*)&s_out2[k8 * 4];
          dotacc4(w, o, a4);
        }
        float ph = fmaxf(hsum4(a4), 0.f);
        if (tid < 128) { s_mup[tid] = ph; g_mup[pb * 128 + tid] = ph; }
        else {
          float y = expf(ph) + 0.5f;
          float sp = (y > 20.f) ? y : log1pf(expf(y));
          s_sgp[tid - 128] = sp; g_sgp[pb * 128 + tid - 128] = sp;
        }
      } else {
        int j2 = tid - 256;
        #pragma unroll 4
        for (int k8 = 0; k8 < 16; ++k8) {
          uint4 w = Wen4[k8 * 256 + j2];
          uint4 o = *(const uint4*)&s_out2[k8 * 4];
          dotacc4(w, o, a4);
        }
        #pragma unroll 4
        for (int k8 = 16; k8 < 32; ++k8) {
          uint4 w = Wen4[k8 * 256 + j2];
          uint4 o = *(const uint4*)&s_xh2[(k8 - 16) * 4];
          dotacc4(w, o, a4);
        }
        float eh = fmaxf(hsum4(a4), 0.f);
        if (j2 < 128) s_ehmu[j2] = eh;
        else { float sq = expf(eh); s_sgq[j2 - 128] = sq; g_sgq[pb * 128 + j2 - 128] = sq; }
      }
    }
    __syncthreads();                       // B2

    // z into padded s_z2 rows (sample = row)
    {
      int l = tid & 127, s0 = tid >> 7;
      float mu = s_ehmu[l] + s_mup[l];
      float sq = s_sgq[l];
      s_z2[s0 * 136 + l]        = (_Float16)(mu + sq * e0);
      s_z2[(s0 + 4) * 136 + l]  = (_Float16)(mu + sq * e1);
      if (tid < 256) s_z2[(s0 + 8) * 136 + l] = (_Float16)(mu + sq * e2);
      if (tid < 128) g_muq[pb * 128 + tid] = mu;
    }
    __syncthreads();                       // B3

    // z_hat via MFMA: wave wv -> cols [16wv,16wv+16), rows = samples
    {
      uint4 a[4];
      #pragma unroll
      for (int ks = 0; ks < 4; ++ks)
        a[ks] = *(const uint4*)&s_z2[l15 * 136 + ks * 32 + quad * 8];
      f32x4 acc = {bz, bz, bz, bz};
      #pragma unroll
      for (int ks = 0; ks < 4; ++ks)
        acc = mfma16(a[ks], BFpz[(wv * 4 + ks) * 64 + lane], acc);
      #pragma unroll
      for (int r = 0; r < 4; ++r) {
        int s = quad * 4 + r;
        if (s < 10)
          s_zh2[s * 136 + 16 * wv + l15] = (_Float16)fmaxf(acc[r], 0.f);
      }
    }
    // gates-x: fdot2, row tid, result to s_gxh
    {
      float4 a4 = {blst, 0.f, 0.f, 0.f};
      #pragma unroll 4
      for (int k8 = 0; k8 < 16; ++k8) {
        uint4 w = Wihx4[k8 * 512 + tid];
        uint4 xv = *(const uint4*)&s_xh2[k8 * 4];
        dotacc4(w, xv, a4);
      }
      s_gxh[tid] = hsum4(a4);
    }
    __syncthreads();                       // B4

    // gates-z via MFMA: wave wv, nt=gate, cols 128*nt + 16*wv + l15
    {
      uint4 a[4];
      #pragma unroll
      for (int ks = 0; ks < 4; ++ks)
        a[ks] = *(const uint4*)&s_zh2[l15 * 136 + ks * 32 + quad * 8];
      #pragma unroll
      for (int nt = 0; nt < 4; ++nt) {
        float gx = s_gxh[128 * nt + 16 * wv + l15];
        f32x4 acc = {gx, gx, gx, gx};
        #pragma unroll
        for (int ks = 0; ks < 4; ++ks)
          acc = mfma16(a[ks], BFihz[((wv * 4 + nt) * 4 + ks) * 64 + lane], acc);
        #pragma unroll
        for (int r = 0; r < 4; ++r) {
          int s = quad * 4 + r;
          if (s < 10)
            s_gz[s * 512 + 128 * nt + 16 * wv + l15] = acc[r];
        }
      }
    }
    // whh B-frags rematerialized per timestep (64 VGPR, serial-section live range)
    uint4 whhf[16];
    #pragma unroll
    for (int i = 0; i < 16; ++i) whhf[i] = BFhh[(wv * 16 + i) * 64 + lane];
    __syncthreads();                       // B5

    // serial LSTM over 10 samples; M=1 broadcast-A MFMA (D rows identical)
    for (int s = 0; s < 10; ++s) {
      uint4 a[4];
      #pragma unroll
      for (int ks = 0; ks < 4; ++ks)
        a[ks] = *(const uint4*)&s_h2[ks * 32 + quad * 8];
      f32x4 acc[4];
      #pragma unroll
      for (int nt = 0; nt < 4; ++nt) {
        float cz = s_gz[s * 512 + 128 * nt + 16 * wv + l15];
        acc[nt] = f32x4{cz, cz, cz, cz};
      }
      __syncthreads();                     // all h reads done before h write
      #pragma unroll
      for (int nt = 0; nt < 4; ++nt)
        #pragma unroll
        for (int ks = 0; ks < 4; ++ks)
          acc[nt] = mfma16(a[ks], whhf[nt * 4 + ks], acc[nt]);
      if (lane < 16) {
        float gi = acc[0][0], gf = acc[1][0], gg = acc[2][0], go = acc[3][0];
        c_reg = sigm(gf) * c_reg + sigm(gi) * tanhf(gg);
        float h = sigm(go) * tanhf(c_reg);
        oacc += h;
        s_h2[16 * wv + lane] = (_Float16)h;
      }
      __syncthreads();
    }
    if (lane < 16) s_out[16 * wv + lane] = oacc * 0.1f;
  }
}

// ---------------- phase 2: ELBO terms, fully parallel ----------------
__global__ __launch_bounds__(256, 2) void phase2_kernel(
    const float* __restrict__ x, const float* __restrict__ beta_p,
    const float* __restrict__ eps,
    const float* __restrict__ g_out, const float* __restrict__ g_muq, const float* __restrict__ g_sgq,
    const float* __restrict__ g_mup, const float* __restrict__ g_sgp,
    const uint4* __restrict__ Wpz4, const float* __restrict__ b_pz,
    const uint4* __restrict__ Wdez4, const uint4* __restrict__ Wdeo4, const float* __restrict__ b_de,
    double* __restrict__ accum)
{
  __shared__ __align__(16) _Float16 s_z2[5120];
  __shared__ __align__(16) _Float16 s_zh2[5120];
  __shared__ __align__(16) unsigned s_out2[256];
  __shared__ __align__(16) float s_muq[512], s_sgq[512], s_mup[512], s_sgp[512];
  __shared__ float s_wred[4];

  const int tid = threadIdx.x;
  const int p0 = blockIdx.x * 4;
  const float beta = beta_p[0];
  float acc_loc = 0.f;

  for (int i = tid; i < 512; i += 256) {
    size_t gi = (size_t)p0 * 128 + i;
    s_muq[i] = g_muq[gi]; s_sgq[i] = g_sgq[gi];
    s_mup[i] = g_mup[gi]; s_sgp[i] = g_sgp[gi];
  }
  {
    int pair = tid >> 6, m = tid & 63;
    const float* o = g_out + (size_t)p0 * 128 + pair * 128;
    s_out2[tid] = packf16(o[2*m], o[2*m + 1]);
  }
  __syncthreads();

  {
    int l = tid & 127;
    int ppb = tid >> 7;
    for (int q = 0; q < 2; ++q) {
      int pp = ppb + 2 * q;
      float mq = s_muq[pp*128 + l], sq = s_sgq[pp*128 + l];
      float mp = s_mup[pp*128 + l], spv = s_sgp[pp*128 + l];
      float inv_sp = 1.f / spv;
      float lsq = __logf(sq), lsp = __logf(spv);
      const float* ep = eps + (size_t)(p0 + pp) * 1280 + l;
      float kl = 0.f;
      #pragma unroll
      for (int s = 0; s < 10; ++s) {
        float e = ep[s * 128];
        float z = mq + sq * e;
        s_z2[(pp * 10 + s) * 128 + l] = (_Float16)z;
        float ap = (z - mp) * inv_sp;
        kl += (-0.5f * e * e - lsq) - (-0.5f * ap * ap - lsp);
      }
      acc_loc -= beta * kl;
    }
  }
  __syncthreads();

  {
    int j = tid & 127, grp = tid >> 7;
    float acc[20];
    float bj = b_pz[j];
    #pragma unroll
    for (int u = 0; u < 20; ++u) acc[u] = bj;
    for (int k8 = 0; k8 < 16; ++k8) {
      uint4 w = Wpz4[k8 * 128 + j];
      #pragma unroll
      for (int u = 0; u < 20; ++u) {
        uint4 zv = *(const uint4*)&s_z2[(grp * 20 + u) * 128 + k8 * 8];
        acc[u] = fdot2(w.x, zv.x, acc[u]); acc[u] = fdot2(w.y, zv.y, acc[u]);
        acc[u] = fdot2(w.z, zv.z, acc[u]); acc[u] = fdot2(w.w, zv.w, acc[u]);
      }
    }
    #pragma unroll
    for (int u = 0; u < 20; ++u)
      s_zh2[(grp * 20 + u) * 128 + j] = (_Float16)fmaxf(acc[u], 0.f);
  }
  __syncthreads();

  for (int dc = 0; dc < 4; ++dc) {
    int d = tid + 256 * dc;
    if (d < 800) {
      float acco[4] = {0.f, 0.f, 0.f, 0.f};
      #pragma unroll 4
      for (int k8 = 0; k8 < 16; ++k8) {
        uint4 w = Wdeo4[k8 * 800 + d];
        #pragma unroll
        for (int pp = 0; pp < 4; ++pp) {
          uint4 ov = *(const uint4*)&s_out2[pp * 64 + k8 * 4];
          acco[pp] = fdot2(w.x, ov.x, acco[pp]); acco[pp] = fdot2(w.y, ov.y, acco[pp]);
          acco[pp] = fdot2(w.z, ov.z, acco[pp]); acco[pp] = fdot2(w.w, ov.w, acco[pp]);
        }
      }
      float bd = b_de[d];
      for (int pp = 0; pp < 4; ++pp) {
        float acc[10];
        #pragma unroll
        for (int s = 0; s < 10; ++s) acc[s] = 0.f;
        #pragma unroll 4
        for (int k8 = 0; k8 < 16; ++k8) {
          uint4 w = Wdez4[k8 * 800 + d];
          #pragma unroll
          for (int s = 0; s < 10; ++s) {
            uint4 zv = *(const uint4*)&s_zh2[(pp * 10 + s) * 128 + k8 * 8];
            acc[s] = fdot2(w.x, zv.x, acc[s]); acc[s] = fdot2(w.y, zv.y, acc[s]);
            acc[s] = fdot2(w.z, zv.z, acc[s]); acc[s] = fdot2(w.w, zv.w, acc[s]);
          }
        }
        int p = p0 + pp, tt2 = p >> 7, bb = p & 127;
        float xd = x[((size_t)bb * TT + tt2) * 800 + d];
        float base = acco[pp] + bd;
        #pragma unroll
        for (int s = 0; s < 10; ++s) {
          float lg = fmaxf(acc[s] + base, 0.f);
          acc_loc += xd * lg - lg - __logf(1.f + __expf(-lg));
        }
      }
    }
  }

  float v = acc_loc;
  #pragma unroll
  for (int off = 32; off > 0; off >>= 1) v += __shfl_down(v, off, 64);
  if ((tid & 63) == 0) s_wred[tid >> 6] = v;
  __syncthreads();
  if (tid == 0) {
    double tot = (double)s_wred[0] + (double)s_wred[1] + (double)s_wred[2] + (double)s_wred[3];
    atomicAdd(accum, tot);
  }
}

__global__ void finalize_kernel(const double* __restrict__ accum, float* __restrict__ out) {
  if (threadIdx.x == 0 && blockIdx.x == 0)
    out[0] = (float)(-accum[0] / 122880.0);   // B*T*S
}

// ---------------- host ----------------
extern "C" void kernel_launch(void* const* d_in, const int* in_sizes, int n_in,
                              void* d_out, int out_size, void* d_ws, size_t ws_size,
                              hipStream_t stream) {
  const float* x    = (const float*)d_in[0];
  const float* beta = (const float*)d_in[1];
  const float* eps  = (const float*)d_in[2];
  const float* W_px = (const float*)d_in[3];
  const float* b_px = (const float*)d_in[4];
  const float* W_pz = (const float*)d_in[5];
  const float* b_pz = (const float*)d_in[6];
  const float* W_pr = (const float*)d_in[7];
  const float* b_pr = (const float*)d_in[8];
  const float* W_en = (const float*)d_in[9];
  const float* b_en = (const float*)d_in[10];
  const float* W_de = (const float*)d_in[11];
  const float* b_de = (const float*)d_in[12];
  const float* W_ih = (const float*)d_in[13];
  const float* W_hh = (const float*)d_in[14];
  const float* b_ih = (const float*)d_in[15];
  const float* b_hh = (const float*)d_in[16];
  float* ws = (float*)d_ws;

  // ws offsets (in 4B units)
  constexpr size_t O_WPX  = 0;                      // 102400 fp32
  constexpr size_t O_WPR  = O_WPX  + 102400;        // 16384 uints (fdot2 pack)
  constexpr size_t O_WEN  = O_WPR  + 16384;         // 32768
  constexpr size_t O_WPZ  = O_WEN  + 32768;         // 8192 (fdot2 pack, phase2)
  constexpr size_t O_WIHX = O_WPZ  + 8192;          // 32768
  constexpr size_t O_BFIZ = O_WIHX + 32768;         // 32768 (MFMA B-frags W_ihz^T)
  constexpr size_t O_BFHH = O_BFIZ + 32768;         // 32768 (MFMA B-frags W_hh^T)
  constexpr size_t O_WDEZ = O_BFHH + 32768;         // 51200
  constexpr size_t O_WDEO = O_WDEZ + 51200;         // 51200
  constexpr size_t O_BL   = O_WDEO + 51200;         // 512
  constexpr size_t O_ACC  = O_BL   + 512;           // 2 (double)
  constexpr size_t O_XHAT = O_ACC  + 4;             // 786432 uints used
  constexpr size_t O_BFPZ = O_XHAT + 786432;        // 8192 (MFMA B-frags W_pz^T)
  constexpr size_t O_OUT  = O_XHAT + 1572864;
  constexpr size_t O_MUQ  = O_OUT  + 1572864;
  constexpr size_t O_SGQ  = O_MUQ  + 1572864;
  constexpr size_t O_MUP  = O_SGQ  + 1572864;
  constexpr size_t O_SGP  = O_MUP  + 1572864;
  (void)O_SGP;

  prep_misc<<<dim3(1), dim3(512), 0, stream>>>(b_ih, b_hh, ws + O_BL, (double*)(ws + O_ACC));

  auto pk = [&](const float* src, size_t off, int J, int rs, int k0, int K) {
    int total = J * (K / 2);
    prep_pack_f16<<<dim3((total + 255) / 256), dim3(256), 0, stream>>>(
        src, (unsigned*)(ws + off), J, rs, k0, total);
  };
  pk(W_pr, O_WPR, 256, 128, 0, 128);
  pk(W_en, O_WEN, 256, 256, 0, 256);
  pk(W_pz, O_WPZ, 128, 128, 0, 128);
  pk(W_ih, O_WIHX, 512, 256, 0, 128);
  pk(W_de, O_WDEZ, 800, 256, 0, 128);
  pk(W_de, O_WDEO, 800, 256, 128, 128);
  // MFMA B-frag packs
  prep_bfrag<<<dim3(128), dim3(256), 0, stream>>>(W_ih, (unsigned*)(ws + O_BFIZ), 256, 128, 4, 0, 32768);
  prep_bfrag<<<dim3(128), dim3(256), 0, stream>>>(W_hh, (unsigned*)(ws + O_BFHH), 128, 0, 4, 0, 32768);
  prep_bfrag<<<dim3(32),  dim3(256), 0, stream>>>(W_pz, (unsigned*)(ws + O_BFPZ), 128, 0, 4, 1, 8192);
  prep_transpose<<<dim3((102400 + 255) / 256), dim3(256), 0, stream>>>(
      W_px, ws + O_WPX, 128, 800, 0, 102400);

  xhat_kernel<<<dim3(1536), dim3(256), 0, stream>>>(x, ws + O_WPX, b_px, (unsigned*)(ws + O_XHAT));

  phase1_kernel<<<dim3(128), dim3(512), 0, stream>>>(
      eps, (const unsigned*)(ws + O_XHAT),
      (const uint4*)(ws + O_WPR), b_pr, (const uint4*)(ws + O_WEN), b_en,
      (const uint4*)(ws + O_BFPZ), b_pz, (const uint4*)(ws + O_WIHX),
      (const uint4*)(ws + O_BFIZ), (const uint4*)(ws + O_BFHH), ws + O_BL,
      ws + O_OUT, ws + O_MUQ, ws + O_SGQ, ws + O_MUP, ws + O_SGP);

  phase2_kernel<<<dim3(3072), dim3(256), 0, stream>>>(
      x, beta, eps, ws + O_OUT, ws + O_MUQ, ws + O_SGQ, ws + O_MUP, ws + O_SGP,
      (const uint4*)(ws + O_WPZ), b_pz,
      (const uint4*)(ws + O_WDEZ), (const uint4*)(ws + O_WDEO), b_de,
      (double*)(ws + O_ACC));

  finalize_kernel<<<dim3(1), dim3(64), 0, stream>>>((const double*)(ws + O_ACC), (float*)d_out);
}